// Round 1
// baseline (407.328 us; speedup 1.0000x reference)
//
#include <hip/hip_runtime.h>

#define H 896
#define NH 14
#define HD 64
#define DFF 4864
#define SEQ 2048
#define NTOK 4096
#define QKVN 1152
#define ASCALE 0.125f   // 1/sqrt(64)

typedef unsigned short bf16_t;
typedef __attribute__((ext_vector_type(8))) short bf16x8;
typedef __attribute__((ext_vector_type(4))) float f32x4;

#define MFMA16(a, b, c) __builtin_amdgcn_mfma_f32_16x16x32_bf16(a, b, c, 0, 0, 0)

__device__ __forceinline__ unsigned short f2bf(float f) {
  unsigned u = __float_as_uint(f);
  u += 0x7fffu + ((u >> 16) & 1u);   // RNE
  return (unsigned short)(u >> 16);
}

__device__ __forceinline__ void gload_lds16(const void* g, void* l) {
  __builtin_amdgcn_global_load_lds(
      (const __attribute__((address_space(1))) unsigned int*)g,
      (__attribute__((address_space(3))) unsigned int*)l, 16, 0, 0);
}

// ---------------- weight convert f32 -> bf16 (4 elems/thread) ----------------
__global__ void cvt_kernel(const float* __restrict__ s, bf16_t* __restrict__ d, int n) {
  const int i = (blockIdx.x * 256 + threadIdx.x) * 4;
  if (i >= n) return;
  const float4 v = *(const float4*)(s + i);
  uint2 o;
  o.x = (unsigned)f2bf(v.x) | ((unsigned)f2bf(v.y) << 16);
  o.y = (unsigned)f2bf(v.z) | ((unsigned)f2bf(v.w) << 16);
  *(uint2*)(d + i) = o;
}

__global__ void bias_cat_kernel(const float* __restrict__ qb, const float* __restrict__ kb,
                                const float* __restrict__ vb, float* __restrict__ out) {
  const int i = blockIdx.x * 256 + threadIdx.x;
  if (i < 1152) out[i] = (i < 896) ? qb[i] : ((i < 1024) ? kb[i - 896] : vb[i - 1024]);
}

// ---------------- RMSNorm: one block per row of 896, f32 in -> bf16 out ------
__global__ __launch_bounds__(256)
void rmsnorm_kernel(const float* __restrict__ x, const float* __restrict__ wt,
                    bf16_t* __restrict__ out) {
  const int row = blockIdx.x;
  const int t = threadIdx.x;
  float4 v = {0.f, 0.f, 0.f, 0.f};
  float ss = 0.f;
  const float4* xr = (const float4*)(x + (size_t)row * H);
  if (t < 224) {
    v = xr[t];
    ss = v.x * v.x + v.y * v.y + v.z * v.z + v.w * v.w;
  }
#pragma unroll
  for (int m = 32; m; m >>= 1) ss += __shfl_xor(ss, m);
  __shared__ float wsum[4];
  if ((t & 63) == 0) wsum[t >> 6] = ss;
  __syncthreads();
  const float rinv = rsqrtf((wsum[0] + wsum[1] + wsum[2] + wsum[3]) * (1.f / 896.f) + 1e-5f);
  if (t < 224) {
    const float4 wv = ((const float4*)wt)[t];
    uint2 o;
    o.x = (unsigned)f2bf(v.x * rinv * wv.x) | ((unsigned)f2bf(v.y * rinv * wv.y) << 16);
    o.y = (unsigned)f2bf(v.z * rinv * wv.z) | ((unsigned)f2bf(v.w * rinv * wv.w) << 16);
    ((uint2*)(out + (size_t)row * H))[t] = o;
  }
}

// ---------------- GEMM out[M][N] = A[M][K] @ B[N][K]^T (+bias | +res) --------
// 128x128 tile, BK=64, 4 waves (2x2), 16x16x32 bf16 MFMA, m97-style staging.
// EPI==0: bf16 out + f32 bias.  EPI==1: f32 out = acc + res.
template <int EPI>
__global__ __launch_bounds__(256, 2)
void gemm_bt(const bf16_t* __restrict__ A, const bf16_t* __restrict__ Bw,
             bf16_t* __restrict__ outb, float* __restrict__ outf,
             const float* __restrict__ bias, const float* __restrict__ res,
             int M, int N, int K) {
  __shared__ bf16_t As[128 * 64];
  __shared__ bf16_t Bs[128 * 64];
  const int tid = threadIdx.x;
  const int lane = tid & 63;
  const int w = tid >> 6;
  const int wr = w >> 1, wc = w & 1;
  const int m0 = blockIdx.y * 128;
  const int n0 = blockIdx.x * 128;

  f32x4 acc[4][4] = {};

  for (int k0 = 0; k0 < K; k0 += 64) {
    __syncthreads();
#pragma unroll
    for (int c = 0; c < 4; ++c) {
      const int e = (c * 256 + tid) * 8;
      const int row = e >> 6;
      const int col = e & 63;
      gload_lds16(A + (size_t)(m0 + row) * K + (k0 + col), As + e);
      gload_lds16(Bw + (size_t)(n0 + row) * K + (k0 + col), Bs + e);
    }
    __syncthreads();
#pragma unroll
    for (int kk = 0; kk < 2; ++kk) {
      const int koff = kk * 32 + (lane >> 4) * 8;
      bf16x8 a[4], b[4];
#pragma unroll
      for (int m = 0; m < 4; ++m)
        a[m] = *(const bf16x8*)(As + (wr * 64 + m * 16 + (lane & 15)) * 64 + koff);
#pragma unroll
      for (int n = 0; n < 4; ++n)
        b[n] = *(const bf16x8*)(Bs + (wc * 64 + n * 16 + (lane & 15)) * 64 + koff);
#pragma unroll
      for (int m = 0; m < 4; ++m)
#pragma unroll
        for (int n = 0; n < 4; ++n)
          acc[m][n] = MFMA16(a[m], b[n], acc[m][n]);
    }
  }

#pragma unroll
  for (int m = 0; m < 4; ++m) {
    const int row = m0 + wr * 64 + m * 16 + ((lane >> 4) << 2);
#pragma unroll
    for (int n = 0; n < 4; ++n) {
      const int col = n0 + wc * 64 + n * 16 + (lane & 15);
      const float bv = (EPI == 0) ? bias[col] : 0.f;
#pragma unroll
      for (int i = 0; i < 4; ++i) {
        const size_t idx = (size_t)(row + i) * N + col;
        if (EPI == 0) outb[idx] = f2bf(acc[m][n][i] + bv);
        else          outf[idx] = acc[m][n][i] + res[idx];
      }
    }
  }
}

// ---------------- fused gate/up GEMM: 128x64 tile, dual B, SiLU(g)*u out -----
__global__ __launch_bounds__(256, 2)
void gateup_kernel(const bf16_t* __restrict__ A, const bf16_t* __restrict__ Wg,
                   const bf16_t* __restrict__ Wu, bf16_t* __restrict__ gu) {
  __shared__ bf16_t As[128 * 64];
  __shared__ bf16_t Bg[64 * 64];
  __shared__ bf16_t Bu[64 * 64];
  const int tid = threadIdx.x;
  const int lane = tid & 63;
  const int w = tid >> 6;
  const int wr = w >> 1, wc = w & 1;
  const int m0 = blockIdx.y * 128;
  const int n0 = blockIdx.x * 64;
  f32x4 ag[4][2] = {}, au[4][2] = {};

  for (int k0 = 0; k0 < 896; k0 += 64) {
    __syncthreads();
#pragma unroll
    for (int c = 0; c < 4; ++c) {
      const int e = (c * 256 + tid) * 8;
      gload_lds16(A + (size_t)(m0 + (e >> 6)) * 896 + k0 + (e & 63), As + e);
    }
#pragma unroll
    for (int c = 0; c < 2; ++c) {
      const int e = (c * 256 + tid) * 8;
      gload_lds16(Wg + (size_t)(n0 + (e >> 6)) * 896 + k0 + (e & 63), Bg + e);
      gload_lds16(Wu + (size_t)(n0 + (e >> 6)) * 896 + k0 + (e & 63), Bu + e);
    }
    __syncthreads();
#pragma unroll
    for (int kk = 0; kk < 2; ++kk) {
      const int koff = kk * 32 + (lane >> 4) * 8;
      bf16x8 a[4], bg[2], bu[2];
#pragma unroll
      for (int m = 0; m < 4; ++m)
        a[m] = *(const bf16x8*)(As + (wr * 64 + m * 16 + (lane & 15)) * 64 + koff);
#pragma unroll
      for (int n = 0; n < 2; ++n) {
        bg[n] = *(const bf16x8*)(Bg + (wc * 32 + n * 16 + (lane & 15)) * 64 + koff);
        bu[n] = *(const bf16x8*)(Bu + (wc * 32 + n * 16 + (lane & 15)) * 64 + koff);
      }
#pragma unroll
      for (int m = 0; m < 4; ++m)
#pragma unroll
        for (int n = 0; n < 2; ++n) {
          ag[m][n] = MFMA16(a[m], bg[n], ag[m][n]);
          au[m][n] = MFMA16(a[m], bu[n], au[m][n]);
        }
    }
  }
#pragma unroll
  for (int m = 0; m < 4; ++m) {
    const int row = m0 + wr * 64 + m * 16 + ((lane >> 4) << 2);
#pragma unroll
    for (int n = 0; n < 2; ++n) {
      const int col = n0 + wc * 32 + n * 16 + (lane & 15);
#pragma unroll
      for (int i = 0; i < 4; ++i) {
        const float g = ag[m][n][i];
        const float u = au[m][n][i];
        const float r = (g / (1.f + __expf(-g))) * u;
        gu[(size_t)(row + i) * DFF + col] = f2bf(r);
      }
    }
  }
}

// ---------------- flash attention (non-causal, GQA 7:1) ----------------------
// grid (16 q-tiles, 14 heads, 2 batch); 4 waves x 32 q-rows; KV tile = 128.
// XOR-swizzle (byte ^= (row&7)<<4) on all LDS tiles; K staged via
// global_load_lds with pre-swizzled SOURCE (linear dest), read swizzled.
__global__ __launch_bounds__(256, 2)
void attn_kernel(const bf16_t* __restrict__ qkv, bf16_t* __restrict__ attn_out) {
  __shared__ bf16_t lds_k[128 * 64];       // K tile (also Q tile in prologue)
  __shared__ bf16_t lds_v[64 * 128];       // V^T tile
  __shared__ bf16_t lds_p[4 * 32 * 128];   // per-wave P
  const int tid = threadIdx.x;
  const int lane = tid & 63;
  const int w = tid >> 6;
  const int qt = blockIdx.x;
  const int h = blockIdx.y;
  const int b = blockIdx.z;
  const int kvh = h / 7;
  const char* Qg = (const char*)(qkv + (size_t)(b * SEQ + qt * 128) * QKVN + h * HD);
  const char* Kg = (const char*)(qkv + (size_t)(b * SEQ) * QKVN + H + kvh * HD);
  const char* Vg = (const char*)(qkv + (size_t)(b * SEQ) * QKVN + 1024 + kvh * HD);

  // stage Q tile (pre-swizzled source), read frags to regs
#pragma unroll
  for (int c = 0; c < 4; ++c) {
    const int e = (c * 256 + tid) * 8;
    const int tok = e >> 6;
    const int sb = ((e & 63) * 2) ^ ((tok & 7) << 4);
    gload_lds16(Qg + (size_t)tok * 2304 + sb, lds_k + e);
  }
  __syncthreads();
  bf16x8 aq[2][2];
#pragma unroll
  for (int m = 0; m < 2; ++m)
#pragma unroll
    for (int kk = 0; kk < 2; ++kk) {
      const int row = w * 32 + m * 16 + (lane & 15);
      const int sb = ((kk * 32 + (lane >> 4) * 8) * 2) ^ ((row & 7) << 4);
      aq[m][kk] = *(const bf16x8*)((const char*)lds_k + row * 128 + sb);
    }

  float m_run[2][4], l_run[2][4];
  f32x4 acc_o[2][4] = {};
#pragma unroll
  for (int m = 0; m < 2; ++m)
#pragma unroll
    for (int i = 0; i < 4; ++i) { m_run[m][i] = -3.0e38f; l_run[m][i] = 0.f; }

  char* pbase = (char*)lds_p + w * 32 * 256;

  for (int kt = 0; kt < 16; ++kt) {
    __syncthreads();
    // stage K tile (pre-swizzled source)
#pragma unroll
    for (int c = 0; c < 4; ++c) {
      const int e = (c * 256 + tid) * 8;
      const int tok = e >> 6;
      const int sb = ((e & 63) * 2) ^ ((tok & 7) << 4);
      gload_lds16(Kg + (size_t)(kt * 128 + tok) * 2304 + sb, lds_k + e);
    }
    // stage V transposed (reg roundtrip, swizzled ds_write)
    {
      const int tok = tid >> 1;
      const int d0 = (tid & 1) * 32;
      bf16x8 vv[4];
#pragma unroll
      for (int j = 0; j < 4; ++j)
        vv[j] = *(const bf16x8*)(Vg + (size_t)(kt * 128 + tok) * 2304 + (size_t)(d0 + j * 8) * 2);
#pragma unroll
      for (int j = 0; j < 4; ++j) {
        const unsigned short* pv = (const unsigned short*)&vv[j];
#pragma unroll
        for (int u = 0; u < 8; ++u) {
          const int d = d0 + j * 8 + u;
          const int byteoff = (d << 8) + (tok << 1);
          *(unsigned short*)((char*)lds_v + (byteoff ^ ((d & 7) << 4))) = pv[u];
        }
      }
    }
    __syncthreads();

    // QK^T : s[m][n] rows = q, cols = key token
    f32x4 s[2][8] = {};
#pragma unroll
    for (int kk = 0; kk < 2; ++kk) {
      bf16x8 bk[8];
#pragma unroll
      for (int n = 0; n < 8; ++n) {
        const int tok = n * 16 + (lane & 15);
        const int sb = ((kk * 32 + (lane >> 4) * 8) * 2) ^ ((tok & 7) << 4);
        bk[n] = *(const bf16x8*)((const char*)lds_k + tok * 128 + sb);
      }
#pragma unroll
      for (int m = 0; m < 2; ++m)
#pragma unroll
        for (int n = 0; n < 8; ++n)
          s[m][n] = MFMA16(aq[m][kk], bk[n], s[m][n]);
    }

    // online softmax + P write (lds_p region is wave-private: no barrier)
#pragma unroll
    for (int m = 0; m < 2; ++m)
#pragma unroll
      for (int i = 0; i < 4; ++i) {
        float mx = -3.0e38f;
#pragma unroll
        for (int n = 0; n < 8; ++n) mx = fmaxf(mx, s[m][n][i]);
        mx = fmaxf(mx, __shfl_xor(mx, 1));
        mx = fmaxf(mx, __shfl_xor(mx, 2));
        mx = fmaxf(mx, __shfl_xor(mx, 4));
        mx = fmaxf(mx, __shfl_xor(mx, 8));
        mx *= ASCALE;
        const float mnew = fmaxf(m_run[m][i], mx);
        const float corr = __expf(m_run[m][i] - mnew);
        float psum = 0.f;
#pragma unroll
        for (int n = 0; n < 8; ++n) {
          const float p = __expf(s[m][n][i] * ASCALE - mnew);
          s[m][n][i] = p;
          psum += p;
        }
        psum += __shfl_xor(psum, 1);
        psum += __shfl_xor(psum, 2);
        psum += __shfl_xor(psum, 4);
        psum += __shfl_xor(psum, 8);
        l_run[m][i] = l_run[m][i] * corr + psum;
        m_run[m][i] = mnew;
#pragma unroll
        for (int n = 0; n < 4; ++n) acc_o[m][n][i] *= corr;
        const int prow = m * 16 + ((lane >> 4) << 2) + i;
#pragma unroll
        for (int n = 0; n < 8; ++n) {
          const int pcb = (n * 16 + (lane & 15)) * 2;
          *(unsigned short*)(pbase + prow * 256 + (pcb ^ ((prow & 7) << 4))) = f2bf(s[m][n][i]);
        }
      }

    // PV: acc_o += P @ V
#pragma unroll
    for (int kk = 0; kk < 4; ++kk) {
      bf16x8 ap[2], bv[4];
#pragma unroll
      for (int m = 0; m < 2; ++m) {
        const int prow = m * 16 + (lane & 15);
        const int pcb = (kk * 32 + (lane >> 4) * 8) * 2;
        ap[m] = *(const bf16x8*)(pbase + prow * 256 + (pcb ^ ((prow & 7) << 4)));
      }
#pragma unroll
      for (int n = 0; n < 4; ++n) {
        const int d = n * 16 + (lane & 15);
        const int cb = (kk * 32 + (lane >> 4) * 8) * 2;
        bv[n] = *(const bf16x8*)((const char*)lds_v + d * 256 + (cb ^ ((d & 7) << 4)));
      }
#pragma unroll
      for (int m = 0; m < 2; ++m)
#pragma unroll
        for (int n = 0; n < 4; ++n)
          acc_o[m][n] = MFMA16(ap[m], bv[n], acc_o[m][n]);
    }
  }

#pragma unroll
  for (int m = 0; m < 2; ++m)
#pragma unroll
    for (int n = 0; n < 4; ++n)
#pragma unroll
      for (int i = 0; i < 4; ++i) {
        const int row = qt * 128 + w * 32 + m * 16 + ((lane >> 4) << 2) + i;
        const int col = n * 16 + (lane & 15);
        attn_out[((size_t)(b * SEQ + row)) * H + h * HD + col] =
            f2bf(acc_o[m][n][i] / l_run[m][i]);
      }
}

// ---------------- launcher ---------------------------------------------------
extern "C" void kernel_launch(void* const* d_in, const int* in_sizes, int n_in,
                              void* d_out, int out_size, void* d_ws, size_t ws_size,
                              hipStream_t stream) {
  const float* x    = (const float*)d_in[0];
  const float* ln1w = (const float*)d_in[3];
  const float* q_w  = (const float*)d_in[4];
  const float* q_b  = (const float*)d_in[5];
  const float* k_w  = (const float*)d_in[6];
  const float* k_b  = (const float*)d_in[7];
  const float* v_w  = (const float*)d_in[8];
  const float* v_b  = (const float*)d_in[9];
  const float* o_w  = (const float*)d_in[10];
  const float* ln2w = (const float*)d_in[11];
  const float* g_w  = (const float*)d_in[12];
  const float* u_w  = (const float*)d_in[13];
  const float* dn_w = (const float*)d_in[14];
  float* out = (float*)d_out;

  char* ws = (char*)d_ws;
  bf16_t* wqkv = (bf16_t*)(ws + 0);         // 1152x896
  bf16_t* wo   = (bf16_t*)(ws + 2064384);   // 896x896
  bf16_t* wg   = (bf16_t*)(ws + 3670016);   // 4864x896
  bf16_t* wu   = (bf16_t*)(ws + 12386304);  // 4864x896
  bf16_t* wd   = (bf16_t*)(ws + 21102592);  // 896x4864
  float*  bqkv = (float*)(ws + 29818880);   // 1152
  bf16_t* hbuf = (bf16_t*)(ws + 29823488);  // 4096x896 (h1, then h2)
  bf16_t* qkv  = (bf16_t*)(ws + 37163520);  // 4096x1152
  bf16_t* attn = (bf16_t*)(ws + 46600704);  // 4096x896
  bf16_t* gu   = (bf16_t*)(ws + 53940736);  // 4096x4864

  // weight conversion
  cvt_kernel<<<784, 256, 0, stream>>>(q_w, wqkv, 802816);
  cvt_kernel<<<112, 256, 0, stream>>>(k_w, wqkv + 802816, 114688);
  cvt_kernel<<<112, 256, 0, stream>>>(v_w, wqkv + 917504, 114688);
  cvt_kernel<<<784, 256, 0, stream>>>(o_w, wo, 802816);
  cvt_kernel<<<4256, 256, 0, stream>>>(g_w, wg, 4358144);
  cvt_kernel<<<4256, 256, 0, stream>>>(u_w, wu, 4358144);
  cvt_kernel<<<4256, 256, 0, stream>>>(dn_w, wd, 4358144);
  bias_cat_kernel<<<5, 256, 0, stream>>>(q_b, k_b, v_b, bqkv);

  // pre-norm attention
  rmsnorm_kernel<<<4096, 256, 0, stream>>>(x, ln1w, hbuf);
  gemm_bt<0><<<dim3(9, 32), 256, 0, stream>>>(hbuf, wqkv, qkv, nullptr, bqkv, nullptr,
                                              4096, 1152, 896);
  attn_kernel<<<dim3(16, 14, 2), 256, 0, stream>>>(qkv, attn);
  gemm_bt<1><<<dim3(7, 32), 256, 0, stream>>>(attn, wo, nullptr, out, nullptr, x,
                                              4096, 896, 896);
  // pre-norm SwiGLU MLP
  rmsnorm_kernel<<<4096, 256, 0, stream>>>(out, ln2w, hbuf);
  gateup_kernel<<<dim3(76, 32), 256, 0, stream>>>(hbuf, wg, wu, gu);
  gemm_bt<1><<<dim3(7, 32), 256, 0, stream>>>(gu, wd, nullptr, out, nullptr, out,
                                              4096, 896, 4864);
}

// Round 2
// 331.417 us; speedup vs baseline: 1.2291x; 1.2291x over previous
//
#include <hip/hip_runtime.h>

#define H 896
#define NH 14
#define HD 64
#define DFF 4864
#define SEQ 2048
#define NTOK 4096
#define QKVN 1152
// ASCALE * log2(e) folded into Q at the QKV epilogue; softmax runs in exp2 domain
#define QSCALE 0.1803368801111244f

typedef unsigned short bf16_t;
typedef __attribute__((ext_vector_type(8))) short bf16x8;
typedef __attribute__((ext_vector_type(4))) float f32x4;

#define MFMA16(a, b, c) __builtin_amdgcn_mfma_f32_16x16x32_bf16(a, b, c, 0, 0, 0)

__device__ __forceinline__ unsigned short f2bf(float f) {
  unsigned u = __float_as_uint(f);
  u += 0x7fffu + ((u >> 16) & 1u);   // RNE
  return (unsigned short)(u >> 16);
}

__device__ __forceinline__ void gload_lds16(const void* g, void* l) {
  __builtin_amdgcn_global_load_lds(
      (const __attribute__((address_space(1))) unsigned int*)g,
      (__attribute__((address_space(3))) unsigned int*)l, 16, 0, 0);
}

// ---------------- fused weight convert f32 -> bf16 --------------------------
__global__ void cvt_all(const float* __restrict__ q_w, const float* __restrict__ k_w,
                        const float* __restrict__ v_w, const float* __restrict__ o_w,
                        const float* __restrict__ g_w, const float* __restrict__ u_w,
                        const float* __restrict__ dn_w, bf16_t* __restrict__ wqkv,
                        bf16_t* __restrict__ wo, bf16_t* __restrict__ wg,
                        bf16_t* __restrict__ wu, bf16_t* __restrict__ wd) {
  const int bx = blockIdx.x;
  const float* src; bf16_t* dst; int base;
  if (bx < 784)        { src = q_w;  dst = wqkv;          base = 0; }
  else if (bx < 896)   { src = k_w;  dst = wqkv + 802816; base = 784; }
  else if (bx < 1008)  { src = v_w;  dst = wqkv + 917504; base = 896; }
  else if (bx < 1792)  { src = o_w;  dst = wo;            base = 1008; }
  else if (bx < 6048)  { src = g_w;  dst = wg;            base = 1792; }
  else if (bx < 10304) { src = u_w;  dst = wu;            base = 6048; }
  else                 { src = dn_w; dst = wd;            base = 10304; }
  const int i = ((bx - base) * 256 + threadIdx.x) * 4;
  const float4 v = *(const float4*)(src + i);
  uint2 o;
  o.x = (unsigned)f2bf(v.x) | ((unsigned)f2bf(v.y) << 16);
  o.y = (unsigned)f2bf(v.z) | ((unsigned)f2bf(v.w) << 16);
  *(uint2*)(dst + i) = o;
}

__global__ void bias_cat_kernel(const float* __restrict__ qb, const float* __restrict__ kb,
                                const float* __restrict__ vb, float* __restrict__ out) {
  const int i = blockIdx.x * 256 + threadIdx.x;
  if (i < 1152) out[i] = (i < 896) ? qb[i] : ((i < 1024) ? kb[i - 896] : vb[i - 1024]);
}

// ---------------- RMSNorm: one block per row of 896, f32 in -> bf16 out ------
__global__ __launch_bounds__(256)
void rmsnorm_kernel(const float* __restrict__ x, const float* __restrict__ wt,
                    bf16_t* __restrict__ out) {
  const int row = blockIdx.x;
  const int t = threadIdx.x;
  float4 v = {0.f, 0.f, 0.f, 0.f};
  float ss = 0.f;
  const float4* xr = (const float4*)(x + (size_t)row * H);
  if (t < 224) {
    v = xr[t];
    ss = v.x * v.x + v.y * v.y + v.z * v.z + v.w * v.w;
  }
#pragma unroll
  for (int m = 32; m; m >>= 1) ss += __shfl_xor(ss, m);
  __shared__ float wsum[4];
  if ((t & 63) == 0) wsum[t >> 6] = ss;
  __syncthreads();
  const float rinv = rsqrtf((wsum[0] + wsum[1] + wsum[2] + wsum[3]) * (1.f / 896.f) + 1e-5f);
  if (t < 224) {
    const float4 wv = ((const float4*)wt)[t];
    uint2 o;
    o.x = (unsigned)f2bf(v.x * rinv * wv.x) | ((unsigned)f2bf(v.y * rinv * wv.y) << 16);
    o.y = (unsigned)f2bf(v.z * rinv * wv.z) | ((unsigned)f2bf(v.w * rinv * wv.w) << 16);
    ((uint2*)(out + (size_t)row * H))[t] = o;
  }
}

// ---------------- GEMM out[M][N] = A[M][K] @ B[N][K]^T (+bias | +res) --------
// BM x 128 tile, BK=64, 4 waves (2x2), 16x16x32 bf16 MFMA.
// EPI==0: bf16 out + f32 bias, cols<896 scaled by QSCALE (QKV proj).
// EPI==1: f32 out = acc + res.
template <int BM, int EPI>
__global__ __launch_bounds__(256, 2)
void gemm_bt(const bf16_t* __restrict__ A, const bf16_t* __restrict__ Bw,
             bf16_t* __restrict__ outb, float* __restrict__ outf,
             const float* __restrict__ bias, const float* __restrict__ res,
             int M, int N, int K) {
  __shared__ bf16_t As[BM * 64];
  __shared__ bf16_t Bs[128 * 64];
  const int tid = threadIdx.x;
  const int lane = tid & 63;
  const int w = tid >> 6;
  const int wr = w >> 1, wc = w & 1;
  const int m0 = blockIdx.y * BM;
  const int n0 = blockIdx.x * 128;
  const int MREP = BM / 32;       // m-fragments per wave
  const int ACH = BM / 32;        // A-staging chunks (BM*64/(256*8))

  f32x4 acc[BM / 32][4] = {};

  for (int k0 = 0; k0 < K; k0 += 64) {
    __syncthreads();
#pragma unroll
    for (int c = 0; c < ACH; ++c) {
      const int e = (c * 256 + tid) * 8;
      gload_lds16(A + (size_t)(m0 + (e >> 6)) * K + (k0 + (e & 63)), As + e);
    }
#pragma unroll
    for (int c = 0; c < 4; ++c) {
      const int e = (c * 256 + tid) * 8;
      gload_lds16(Bw + (size_t)(n0 + (e >> 6)) * K + (k0 + (e & 63)), Bs + e);
    }
    __syncthreads();
#pragma unroll
    for (int kk = 0; kk < 2; ++kk) {
      const int koff = kk * 32 + (lane >> 4) * 8;
      bf16x8 a[BM / 32], b[4];
#pragma unroll
      for (int m = 0; m < MREP; ++m)
        a[m] = *(const bf16x8*)(As + (wr * (BM / 2) + m * 16 + (lane & 15)) * 64 + koff);
#pragma unroll
      for (int n = 0; n < 4; ++n)
        b[n] = *(const bf16x8*)(Bs + (wc * 64 + n * 16 + (lane & 15)) * 64 + koff);
#pragma unroll
      for (int m = 0; m < MREP; ++m)
#pragma unroll
        for (int n = 0; n < 4; ++n)
          acc[m][n] = MFMA16(a[m], b[n], acc[m][n]);
    }
  }

#pragma unroll
  for (int m = 0; m < MREP; ++m) {
    const int row = m0 + wr * (BM / 2) + m * 16 + ((lane >> 4) << 2);
#pragma unroll
    for (int n = 0; n < 4; ++n) {
      const int col = n0 + wc * 64 + n * 16 + (lane & 15);
      float bv = 0.f, sc = 1.f;
      if (EPI == 0) { bv = bias[col]; sc = (col < 896) ? QSCALE : 1.f; }
#pragma unroll
      for (int i = 0; i < 4; ++i) {
        const size_t idx = (size_t)(row + i) * N + col;
        if (EPI == 0) outb[idx] = f2bf((acc[m][n][i] + bv) * sc);
        else          outf[idx] = acc[m][n][i] + res[idx];
      }
    }
  }
}

// ---------------- fused gate/up GEMM: 128x64 tile, dual B, SiLU(g)*u out -----
__global__ __launch_bounds__(256, 2)
void gateup_kernel(const bf16_t* __restrict__ A, const bf16_t* __restrict__ Wg,
                   const bf16_t* __restrict__ Wu, bf16_t* __restrict__ gu) {
  __shared__ bf16_t As[128 * 64];
  __shared__ bf16_t Bg[64 * 64];
  __shared__ bf16_t Bu[64 * 64];
  const int tid = threadIdx.x;
  const int lane = tid & 63;
  const int w = tid >> 6;
  const int wr = w >> 1, wc = w & 1;
  const int m0 = blockIdx.y * 128;
  const int n0 = blockIdx.x * 64;
  f32x4 ag[4][2] = {}, au[4][2] = {};

  for (int k0 = 0; k0 < 896; k0 += 64) {
    __syncthreads();
#pragma unroll
    for (int c = 0; c < 4; ++c) {
      const int e = (c * 256 + tid) * 8;
      gload_lds16(A + (size_t)(m0 + (e >> 6)) * 896 + k0 + (e & 63), As + e);
    }
#pragma unroll
    for (int c = 0; c < 2; ++c) {
      const int e = (c * 256 + tid) * 8;
      gload_lds16(Wg + (size_t)(n0 + (e >> 6)) * 896 + k0 + (e & 63), Bg + e);
      gload_lds16(Wu + (size_t)(n0 + (e >> 6)) * 896 + k0 + (e & 63), Bu + e);
    }
    __syncthreads();
#pragma unroll
    for (int kk = 0; kk < 2; ++kk) {
      const int koff = kk * 32 + (lane >> 4) * 8;
      bf16x8 a[4], bg[2], bu[2];
#pragma unroll
      for (int m = 0; m < 4; ++m)
        a[m] = *(const bf16x8*)(As + (wr * 64 + m * 16 + (lane & 15)) * 64 + koff);
#pragma unroll
      for (int n = 0; n < 2; ++n) {
        bg[n] = *(const bf16x8*)(Bg + (wc * 32 + n * 16 + (lane & 15)) * 64 + koff);
        bu[n] = *(const bf16x8*)(Bu + (wc * 32 + n * 16 + (lane & 15)) * 64 + koff);
      }
#pragma unroll
      for (int m = 0; m < 4; ++m)
#pragma unroll
        for (int n = 0; n < 2; ++n) {
          ag[m][n] = MFMA16(a[m], bg[n], ag[m][n]);
          au[m][n] = MFMA16(a[m], bu[n], au[m][n]);
        }
    }
  }
#pragma unroll
  for (int m = 0; m < 4; ++m) {
    const int row = m0 + wr * 64 + m * 16 + ((lane >> 4) << 2);
#pragma unroll
    for (int n = 0; n < 2; ++n) {
      const int col = n0 + wc * 32 + n * 16 + (lane & 15);
#pragma unroll
      for (int i = 0; i < 4; ++i) {
        const float g = ag[m][n][i];
        const float u = au[m][n][i];
        const float r = (g / (1.f + __expf(-g))) * u;
        gu[(size_t)(row + i) * DFF + col] = f2bf(r);
      }
    }
  }
}

// ---------------- flash attention v2 (non-causal, GQA 7:1) -------------------
// grid (16,14,2); 8 waves x 16 q-rows; KV tile 128. Q pre-scaled by
// ASCALE*log2(e) -> softmax in exp2 domain. Chunked wave-private P (32-kv
// slices, stride-80B). V regs prefetched one tile ahead. XOR-swizzled K/V LDS.
__global__ __launch_bounds__(512, 4)
void attn_kernel(const bf16_t* __restrict__ qkv, bf16_t* __restrict__ attn_out) {
  __shared__ bf16_t lds_k[128 * 64];   // 16 KB (Q tile in prologue, then K)
  __shared__ bf16_t lds_v[64 * 128];   // 16 KB V^T
  __shared__ bf16_t lds_p[8 * 640];    // 10 KB: 8 waves x 16 rows x 40 (80B stride)
  const int tid = threadIdx.x;
  const int lane = tid & 63;
  const int w = tid >> 6;
  const int qt = blockIdx.x;
  const int h = blockIdx.y;
  const int b = blockIdx.z;
  const int kvh = h / 7;
  const char* Qg = (const char*)(qkv + (size_t)(b * SEQ + qt * 128) * QKVN + h * HD);
  const char* Kg = (const char*)(qkv + (size_t)(b * SEQ) * QKVN + H + kvh * HD);
  const char* Vg = (const char*)(qkv + (size_t)(b * SEQ) * QKVN + 1024 + kvh * HD);

  // stage Q tile (pre-swizzled source), read frags to regs
#pragma unroll
  for (int c = 0; c < 2; ++c) {
    const int e = (c * 512 + tid) * 8;
    const int tok = e >> 6;
    const int sb = ((e & 63) * 2) ^ ((tok & 7) << 4);
    gload_lds16(Qg + (size_t)tok * 2304 + sb, lds_k + e);
  }
  __syncthreads();
  bf16x8 aq[2];
  {
    const int qrow = w * 16 + (lane & 15);
#pragma unroll
    for (int kk = 0; kk < 2; ++kk) {
      const int sb = ((kk * 32 + (lane >> 4) * 8) * 2) ^ ((qrow & 7) << 4);
      aq[kk] = *(const bf16x8*)((const char*)lds_k + qrow * 128 + sb);
    }
  }

  // V staging geometry: wave pair covers 16 d's x 128 tokens
  const int vtok = (w & 1) * 64 + lane;
  const int vdg = w >> 1;   // 0..3 -> d base vdg*16

  bf16x8 vcur[2], vnxt[2];
#pragma unroll
  for (int j = 0; j < 2; ++j)
    vcur[j] = *(const bf16x8*)(Vg + (size_t)vtok * 2304 + (size_t)(vdg * 16 + j * 8) * 2);

  float m_run[4], l_run[4];
  f32x4 acc_o[4] = {};
#pragma unroll
  for (int i = 0; i < 4; ++i) { m_run[i] = -1.0e30f; l_run[i] = 0.f; }

  char* pb = (char*)lds_p + w * 1280;

  for (int kt = 0; kt < 16; ++kt) {
    __syncthreads();   // waves done reading lds_k (Q/prev K) and lds_v
    // stage K tile (pre-swizzled source, linear LDS dest)
#pragma unroll
    for (int c = 0; c < 2; ++c) {
      const int e = (c * 512 + tid) * 8;
      const int tok = e >> 6;
      const int sb = ((e & 63) * 2) ^ ((tok & 7) << 4);
      gload_lds16(Kg + (size_t)(kt * 128 + tok) * 2304 + sb, lds_k + e);
    }
    // prefetch next V tile into regs (latency hides under this tile's compute)
    if (kt < 15) {
#pragma unroll
      for (int j = 0; j < 2; ++j)
        vnxt[j] = *(const bf16x8*)(Vg + (size_t)((kt + 1) * 128 + vtok) * 2304 +
                                   (size_t)(vdg * 16 + j * 8) * 2);
    }
    // write current V tile transposed into LDS (wave-uniform d -> conflict-free)
#pragma unroll
    for (int j = 0; j < 2; ++j) {
      const unsigned short* pv = (const unsigned short*)&vcur[j];
#pragma unroll
      for (int u = 0; u < 8; ++u) {
        const int d = vdg * 16 + j * 8 + u;
        const int by = (d << 8) + (vtok << 1);
        *(unsigned short*)((char*)lds_v + (by ^ ((d & 7) << 4))) = pv[u];
      }
    }
    __syncthreads();

    // QK^T (Q pre-scaled): s[n][i], row q=(lane>>4)*4+i, col kv=n*16+(lane&15)
    f32x4 s[8] = {};
#pragma unroll
    for (int kk = 0; kk < 2; ++kk) {
#pragma unroll
      for (int half = 0; half < 2; ++half) {
        bf16x8 bk[4];
#pragma unroll
        for (int n = 0; n < 4; ++n) {
          const int tok = (half * 4 + n) * 16 + (lane & 15);
          const int sb = ((kk * 32 + (lane >> 4) * 8) * 2) ^ ((tok & 7) << 4);
          bk[n] = *(const bf16x8*)((const char*)lds_k + tok * 128 + sb);
        }
        __builtin_amdgcn_s_setprio(1);
#pragma unroll
        for (int n = 0; n < 4; ++n)
          s[half * 4 + n] = MFMA16(aq[kk], bk[n], s[half * 4 + n]);
        __builtin_amdgcn_s_setprio(0);
      }
    }

    // online softmax (exp2 domain) with defer-max
#pragma unroll
    for (int i = 0; i < 4; ++i) {
      float mx = fmaxf(fmaxf(fmaxf(s[0][i], s[1][i]), fmaxf(s[2][i], s[3][i])),
                       fmaxf(fmaxf(s[4][i], s[5][i]), fmaxf(s[6][i], s[7][i])));
      mx = fmaxf(mx, __shfl_xor(mx, 1));
      mx = fmaxf(mx, __shfl_xor(mx, 2));
      mx = fmaxf(mx, __shfl_xor(mx, 4));
      mx = fmaxf(mx, __shfl_xor(mx, 8));
      if (!__all(mx <= m_run[i] + 11.5f)) {
        const float mnew = fmaxf(m_run[i], mx);
        const float corr = exp2f(m_run[i] - mnew);
        m_run[i] = mnew;
        l_run[i] *= corr;
#pragma unroll
        for (int n = 0; n < 4; ++n) acc_o[n][i] *= corr;
      }
      float psum = 0.f;
#pragma unroll
      for (int n = 0; n < 8; ++n) {
        const float p = exp2f(s[n][i] - m_run[i]);
        s[n][i] = p;
        psum += p;
      }
      psum += __shfl_xor(psum, 1);
      psum += __shfl_xor(psum, 2);
      psum += __shfl_xor(psum, 4);
      psum += __shfl_xor(psum, 8);
      l_run[i] += psum;
    }

    // PV in 32-kv chunks through wave-private P slice
#pragma unroll
    for (int kk = 0; kk < 4; ++kk) {
#pragma unroll
      for (int n2 = 0; n2 < 2; ++n2)
#pragma unroll
        for (int i = 0; i < 4; ++i) {
          const int r = ((lane >> 4) << 2) + i;
          *(unsigned short*)(pb + r * 80 + (n2 * 16 + (lane & 15)) * 2) =
              f2bf(s[kk * 2 + n2][i]);
        }
      const bf16x8 ap = *(const bf16x8*)(pb + (lane & 15) * 80 + (lane >> 4) * 16);
      bf16x8 bv[4];
#pragma unroll
      for (int n = 0; n < 4; ++n) {
        const int d = n * 16 + (lane & 15);
        const int cb = (kk * 32 + (lane >> 4) * 8) * 2;
        bv[n] = *(const bf16x8*)((const char*)lds_v + d * 256 + (cb ^ ((d & 7) << 4)));
      }
      __builtin_amdgcn_s_setprio(1);
#pragma unroll
      for (int n = 0; n < 4; ++n)
        acc_o[n] = MFMA16(ap, bv[n], acc_o[n]);
      __builtin_amdgcn_s_setprio(0);
    }
    vcur[0] = vnxt[0];
    vcur[1] = vnxt[1];
  }

#pragma unroll
  for (int n = 0; n < 4; ++n)
#pragma unroll
    for (int i = 0; i < 4; ++i) {
      const int row = qt * 128 + w * 16 + ((lane >> 4) << 2) + i;
      const int col = n * 16 + (lane & 15);
      attn_out[((size_t)(b * SEQ + row)) * H + h * HD + col] =
          f2bf(acc_o[n][i] / l_run[i]);
    }
}

// ---------------- launcher ---------------------------------------------------
extern "C" void kernel_launch(void* const* d_in, const int* in_sizes, int n_in,
                              void* d_out, int out_size, void* d_ws, size_t ws_size,
                              hipStream_t stream) {
  const float* x    = (const float*)d_in[0];
  const float* ln1w = (const float*)d_in[3];
  const float* q_w  = (const float*)d_in[4];
  const float* q_b  = (const float*)d_in[5];
  const float* k_w  = (const float*)d_in[6];
  const float* k_b  = (const float*)d_in[7];
  const float* v_w  = (const float*)d_in[8];
  const float* v_b  = (const float*)d_in[9];
  const float* o_w  = (const float*)d_in[10];
  const float* ln2w = (const float*)d_in[11];
  const float* g_w  = (const float*)d_in[12];
  const float* u_w  = (const float*)d_in[13];
  const float* dn_w = (const float*)d_in[14];
  float* out = (float*)d_out;

  char* ws = (char*)d_ws;
  bf16_t* wqkv = (bf16_t*)(ws + 0);         // 1152x896
  bf16_t* wo   = (bf16_t*)(ws + 2064384);   // 896x896
  bf16_t* wg   = (bf16_t*)(ws + 3670016);   // 4864x896
  bf16_t* wu   = (bf16_t*)(ws + 12386304);  // 4864x896
  bf16_t* wd   = (bf16_t*)(ws + 21102592);  // 896x4864
  float*  bqkv = (float*)(ws + 29818880);   // 1152
  bf16_t* hbuf = (bf16_t*)(ws + 29823488);  // 4096x896 (h1, then h2)
  bf16_t* qkv  = (bf16_t*)(ws + 37163520);  // 4096x1152
  bf16_t* attn = (bf16_t*)(ws + 46600704);  // 4096x896
  bf16_t* gu   = (bf16_t*)(ws + 53940736);  // 4096x4864

  // weight conversion (single fused launch) + bias concat
  cvt_all<<<14560, 256, 0, stream>>>(q_w, k_w, v_w, o_w, g_w, u_w, dn_w,
                                     wqkv, wo, wg, wu, wd);
  bias_cat_kernel<<<5, 256, 0, stream>>>(q_b, k_b, v_b, bqkv);

  // pre-norm attention
  rmsnorm_kernel<<<4096, 256, 0, stream>>>(x, ln1w, hbuf);
  gemm_bt<64, 0><<<dim3(9, 64), 256, 0, stream>>>(hbuf, wqkv, qkv, nullptr, bqkv,
                                                  nullptr, 4096, 1152, 896);
  attn_kernel<<<dim3(16, 14, 2), 512, 0, stream>>>(qkv, attn);
  gemm_bt<64, 1><<<dim3(7, 64), 256, 0, stream>>>(attn, wo, nullptr, out, nullptr, x,
                                                  4096, 896, 896);
  // pre-norm SwiGLU MLP
  rmsnorm_kernel<<<4096, 256, 0, stream>>>(out, ln2w, hbuf);
  gateup_kernel<<<dim3(76, 32), 256, 0, stream>>>(hbuf, wg, wu, gu);
  gemm_bt<64, 1><<<dim3(7, 64), 256, 0, stream>>>(gu, wd, nullptr, out, nullptr, out,
                                                  4096, 896, 4864);
}

// Round 3
// 308.219 us; speedup vs baseline: 1.3216x; 1.0753x over previous
//
#include <hip/hip_runtime.h>

#define H 896
#define NH 14
#define HD 64
#define DFF 4864
#define SEQ 2048
#define NTOK 4096
#define QKVN 1152
// ASCALE * log2(e), folded into q-weights/bias at conversion; softmax in exp2 domain
#define QSCALE 0.1803368801111244f

typedef unsigned short bf16_t;
typedef __attribute__((ext_vector_type(8))) short bf16x8;
typedef __attribute__((ext_vector_type(4))) float f32x4;

#define MFMA16(a, b, c) __builtin_amdgcn_mfma_f32_16x16x32_bf16(a, b, c, 0, 0, 0)

__device__ __forceinline__ unsigned short f2bf(float f) {
  unsigned u = __float_as_uint(f);
  u += 0x7fffu + ((u >> 16) & 1u);   // RNE
  return (unsigned short)(u >> 16);
}

__device__ __forceinline__ unsigned cvtpk(float lo, float hi) {
  unsigned r;
  asm("v_cvt_pk_bf16_f32 %0, %1, %2" : "=v"(r) : "v"(lo), "v"(hi));
  return r;
}

__device__ __forceinline__ void gload_lds16(const void* g, void* l) {
  __builtin_amdgcn_global_load_lds(
      (const __attribute__((address_space(1))) unsigned int*)g,
      (__attribute__((address_space(3))) unsigned int*)l, 16, 0, 0);
}

// ---------------- fused weight convert f32 -> bf16 (QSCALE folded into q) ----
__global__ void cvt_all(const float* __restrict__ q_w, const float* __restrict__ k_w,
                        const float* __restrict__ v_w, const float* __restrict__ o_w,
                        const float* __restrict__ g_w, const float* __restrict__ u_w,
                        const float* __restrict__ dn_w, bf16_t* __restrict__ wqkv,
                        bf16_t* __restrict__ wo, bf16_t* __restrict__ wg,
                        bf16_t* __restrict__ wu, bf16_t* __restrict__ wd) {
  const int bx = blockIdx.x;
  const float* src; bf16_t* dst; int base; float sc = 1.f;
  if (bx < 784)        { src = q_w;  dst = wqkv;          base = 0;  sc = QSCALE; }
  else if (bx < 896)   { src = k_w;  dst = wqkv + 802816; base = 784; }
  else if (bx < 1008)  { src = v_w;  dst = wqkv + 917504; base = 896; }
  else if (bx < 1792)  { src = o_w;  dst = wo;            base = 1008; }
  else if (bx < 6048)  { src = g_w;  dst = wg;            base = 1792; }
  else if (bx < 10304) { src = u_w;  dst = wu;            base = 6048; }
  else                 { src = dn_w; dst = wd;            base = 10304; }
  const int i = ((bx - base) * 256 + threadIdx.x) * 4;
  const float4 v = *(const float4*)(src + i);
  uint2 o;
  o.x = (unsigned)f2bf(v.x * sc) | ((unsigned)f2bf(v.y * sc) << 16);
  o.y = (unsigned)f2bf(v.z * sc) | ((unsigned)f2bf(v.w * sc) << 16);
  *(uint2*)(dst + i) = o;
}

__global__ void bias_cat_kernel(const float* __restrict__ qb, const float* __restrict__ kb,
                                const float* __restrict__ vb, float* __restrict__ out) {
  const int i = blockIdx.x * 256 + threadIdx.x;
  if (i < 1152)
    out[i] = (i < 896) ? qb[i] * QSCALE : ((i < 1024) ? kb[i - 896] : vb[i - 1024]);
}

// ---------------- RMSNorm: one block per row of 896, f32 in -> bf16 out ------
__global__ __launch_bounds__(256)
void rmsnorm_kernel(const float* __restrict__ x, const float* __restrict__ wt,
                    bf16_t* __restrict__ out) {
  const int row = blockIdx.x;
  const int t = threadIdx.x;
  float4 v = {0.f, 0.f, 0.f, 0.f};
  float ss = 0.f;
  const float4* xr = (const float4*)(x + (size_t)row * H);
  if (t < 224) {
    v = xr[t];
    ss = v.x * v.x + v.y * v.y + v.z * v.z + v.w * v.w;
  }
#pragma unroll
  for (int m = 32; m; m >>= 1) ss += __shfl_xor(ss, m);
  __shared__ float wsum[4];
  if ((t & 63) == 0) wsum[t >> 6] = ss;
  __syncthreads();
  const float rinv = rsqrtf((wsum[0] + wsum[1] + wsum[2] + wsum[3]) * (1.f / 896.f) + 1e-5f);
  if (t < 224) {
    const float4 wv = ((const float4*)wt)[t];
    uint2 o;
    o.x = (unsigned)f2bf(v.x * rinv * wv.x) | ((unsigned)f2bf(v.y * rinv * wv.y) << 16);
    o.y = (unsigned)f2bf(v.z * rinv * wv.z) | ((unsigned)f2bf(v.w * rinv * wv.w) << 16);
    ((uint2*)(out + (size_t)row * H))[t] = o;
  }
}

// ---------------- GEMM out[M][N] = A[M][K] @ B[N][K]^T (+bias | +res) --------
// BM x 128 tile, BK=64, 4 waves (2x2). 1-D grid (nb%8==0) with bijective XCD
// swizzle + y-grouped order: each XCD owns 8 consecutive row-blocks; B-panels
// reused by 8 consecutive blocks (L2), A-panels cycle at distance nbx.
template <int BM, int EPI>
__global__ __launch_bounds__(256, 2)
void gemm_bt(const bf16_t* __restrict__ A, const bf16_t* __restrict__ Bw,
             bf16_t* __restrict__ outb, float* __restrict__ outf,
             const float* __restrict__ bias, const float* __restrict__ res,
             int M, int N, int K) {
  __shared__ bf16_t As[BM * 64];
  __shared__ bf16_t Bs[128 * 64];
  const int tid = threadIdx.x;
  const int lane = tid & 63;
  const int w = tid >> 6;
  const int wr = w >> 1, wc = w & 1;
  // XCD-swizzled block mapping
  const int local = blockIdx.x >> 3;     // 0..cs-1 (cs = nbx*8)
  const int xcd = blockIdx.x & 7;
  const int m0 = (xcd * 8 + (local & 7)) * BM;
  const int n0 = (local >> 3) * 128;
  const int MREP = BM / 32;
  const int ACH = BM / 32;

  f32x4 acc[BM / 32][4] = {};

  for (int k0 = 0; k0 < K; k0 += 64) {
    __syncthreads();
#pragma unroll
    for (int c = 0; c < ACH; ++c) {
      const int e = (c * 256 + tid) * 8;
      gload_lds16(A + (size_t)(m0 + (e >> 6)) * K + (k0 + (e & 63)), As + e);
    }
#pragma unroll
    for (int c = 0; c < 4; ++c) {
      const int e = (c * 256 + tid) * 8;
      gload_lds16(Bw + (size_t)(n0 + (e >> 6)) * K + (k0 + (e & 63)), Bs + e);
    }
    __syncthreads();
#pragma unroll
    for (int kk = 0; kk < 2; ++kk) {
      const int koff = kk * 32 + (lane >> 4) * 8;
      bf16x8 a[BM / 32], b[4];
#pragma unroll
      for (int m = 0; m < MREP; ++m)
        a[m] = *(const bf16x8*)(As + (wr * (BM / 2) + m * 16 + (lane & 15)) * 64 + koff);
#pragma unroll
      for (int n = 0; n < 4; ++n)
        b[n] = *(const bf16x8*)(Bs + (wc * 64 + n * 16 + (lane & 15)) * 64 + koff);
#pragma unroll
      for (int m = 0; m < MREP; ++m)
#pragma unroll
        for (int n = 0; n < 4; ++n)
          acc[m][n] = MFMA16(a[m], b[n], acc[m][n]);
    }
  }

#pragma unroll
  for (int m = 0; m < MREP; ++m) {
    const int row = m0 + wr * (BM / 2) + m * 16 + ((lane >> 4) << 2);
#pragma unroll
    for (int n = 0; n < 4; ++n) {
      const int col = n0 + wc * 64 + n * 16 + (lane & 15);
      const float bv = (EPI == 0) ? bias[col] : 0.f;
#pragma unroll
      for (int i = 0; i < 4; ++i) {
        const size_t idx = (size_t)(row + i) * N + col;
        if (EPI == 0) outb[idx] = f2bf(acc[m][n][i] + bv);
        else          outf[idx] = acc[m][n][i] + res[idx];
      }
    }
  }
}

// ---------------- fused gate/up GEMM v2 ---------------------------------------
// 128x64 tile, 4 waves: waves 0-1 gate (rows w*64), waves 2-3 up. 32 MFMA per
// wave per k-step (m97 density). f32 LDS exchange for silu(g)*u epilogue.
// XCD swizzle: grid 2432 = 8 chunks x (76 x-blocks x 4 y-blocks).
__global__ __launch_bounds__(256, 2)
void gateup_kernel(const bf16_t* __restrict__ A, const bf16_t* __restrict__ Wg,
                   const bf16_t* __restrict__ Wu, bf16_t* __restrict__ gu) {
  __shared__ __align__(16) char gsm[32768];
  bf16_t* As = (bf16_t*)gsm;              // 128x64 = 16 KB
  bf16_t* Bg = (bf16_t*)(gsm + 16384);    // 64x64 = 8 KB
  bf16_t* Bu = (bf16_t*)(gsm + 24576);    // 64x64 = 8 KB
  const int tid = threadIdx.x;
  const int lane = tid & 63;
  const int q = lane & 15;
  const int g = lane >> 4;
  const int w = tid >> 6;
  const int local = blockIdx.x >> 3;      // 0..303
  const int xcd = blockIdx.x & 7;
  const int m0 = (xcd * 4 + (local & 3)) * 128;
  const int n0 = (local >> 2) * 64;
  const int rbase = (w & 1) * 64;
  const bf16_t* Bsel = (w < 2) ? Bg : Bu;

  f32x4 acc[4][4] = {};

  for (int k0 = 0; k0 < 896; k0 += 64) {
    __syncthreads();
#pragma unroll
    for (int c = 0; c < 4; ++c) {
      const int e = (c * 256 + tid) * 8;
      gload_lds16(A + (size_t)(m0 + (e >> 6)) * 896 + k0 + (e & 63), As + e);
    }
#pragma unroll
    for (int c = 0; c < 2; ++c) {
      const int e = (c * 256 + tid) * 8;
      gload_lds16(Wg + (size_t)(n0 + (e >> 6)) * 896 + k0 + (e & 63), Bg + e);
      gload_lds16(Wu + (size_t)(n0 + (e >> 6)) * 896 + k0 + (e & 63), Bu + e);
    }
    __syncthreads();
#pragma unroll
    for (int kk = 0; kk < 2; ++kk) {
      const int koff = kk * 32 + g * 8;
      bf16x8 a[4], b[4];
#pragma unroll
      for (int m = 0; m < 4; ++m)
        a[m] = *(const bf16x8*)(As + (rbase + m * 16 + q) * 64 + koff);
#pragma unroll
      for (int n = 0; n < 4; ++n)
        b[n] = *(const bf16x8*)(Bsel + (n * 16 + q) * 64 + koff);
#pragma unroll
      for (int m = 0; m < 4; ++m)
#pragma unroll
        for (int n = 0; n < 4; ++n)
          acc[m][n] = MFMA16(a[m], b[n], acc[m][n]);
    }
  }

  // exchange up through LDS (f32), fuse silu(g)*u in lower waves
  __syncthreads();
  float* ex = (float*)gsm;   // 2 x 16 KB
  if (w >= 2) {
    float* dst = ex + (w - 2) * 4096;
#pragma unroll
    for (int m = 0; m < 4; ++m)
#pragma unroll
      for (int n = 0; n < 4; ++n)
#pragma unroll
        for (int i = 0; i < 4; ++i)
          dst[(m * 16 + g * 4 + i) * 64 + n * 16 + q] = acc[m][n][i];
  }
  __syncthreads();
  if (w < 2) {
    const float* src = ex + w * 4096;
#pragma unroll
    for (int m = 0; m < 4; ++m)
#pragma unroll
      for (int n = 0; n < 4; ++n)
#pragma unroll
        for (int i = 0; i < 4; ++i) {
          const float gv = acc[m][n][i];
          const float uv = src[(m * 16 + g * 4 + i) * 64 + n * 16 + q];
          const float r = (gv / (1.f + __expf(-gv))) * uv;
          const int row = m0 + rbase + m * 16 + g * 4 + i;
          gu[(size_t)row * DFF + n * 16 + q + n0] = f2bf(r);
        }
  }
}

// ---------------- flash attention v3: swapped QK^T (T12), lane-local softmax --
// grid (16,14,2); 8 waves x 16 q-rows; KVBLK=128. MFMA(K,Q) -> D[kv][q]:
// lane (q=lane&15, g=lane>>4) owns 32 scores for one q. K rows PERMUTED in LDS
// (row=32s+16b+4g+i <- kv=32s+8g+4b+i) so cvt_pk'd P pairs form PV B-frags
// entirely in-lane (no exchange, no P-LDS). PV = MFMA(V^T, P) -> O^T[d][q];
// LDS-bounce transpose epilogue.
__global__ __launch_bounds__(512, 4)
void attn_kernel(const bf16_t* __restrict__ qkv, bf16_t* __restrict__ attn_out) {
  __shared__ __align__(16) char smem[32768];
  bf16_t* lds_k = (bf16_t*)smem;          // 16 KB: Q tile, then K tiles
  char* lds_v = smem + 16384;             // 16 KB: V^T
  const int tid = threadIdx.x;
  const int lane = tid & 63;
  const int q = lane & 15;
  const int g = lane >> 4;
  const int w = tid >> 6;
  const int qt = blockIdx.x;
  const int h = blockIdx.y;
  const int b = blockIdx.z;
  const int kvh = h / 7;
  const char* Qg = (const char*)(qkv + (size_t)(b * SEQ + qt * 128) * QKVN + h * HD);
  const char* Kg = (const char*)(qkv + (size_t)(b * SEQ) * QKVN + H + kvh * HD);
  const char* Vg = (const char*)(qkv + (size_t)(b * SEQ) * QKVN + 1024 + kvh * HD);

  // stage Q tile (pre-swizzled source), read B-operand frags
#pragma unroll
  for (int c = 0; c < 2; ++c) {
    const int e = (c * 512 + tid) * 8;
    const int tok = e >> 6;
    const int sb = ((e & 63) * 2) ^ ((tok & 7) << 4);
    gload_lds16(Qg + (size_t)tok * 2304 + sb, lds_k + e);
  }
  __syncthreads();
  bf16x8 aq[2];
  {
    const int qrow = w * 16 + q;
#pragma unroll
    for (int kk = 0; kk < 2; ++kk) {
      const int sb = ((kk * 32 + g * 8) * 2) ^ ((qrow & 7) << 4);
      aq[kk] = *(const bf16x8*)((const char*)lds_k + qrow * 128 + sb);
    }
  }

  // V staging geometry: wave pair covers 16 d's x 128 tokens
  const int vtok = (w & 1) * 64 + lane;
  const int vdg = w >> 1;

  bf16x8 vcur[2], vnxt[2];
#pragma unroll
  for (int j = 0; j < 2; ++j)
    vcur[j] = *(const bf16x8*)(Vg + (size_t)vtok * 2304 + (size_t)(vdg * 16 + j * 8) * 2);

  float m_run = -1.0e30f, l_run = 0.f;
  f32x4 acc[4] = {};

  for (int kt = 0; kt < 16; ++kt) {
    __syncthreads();
    // stage K tile, PERMUTED rows + pre-swizzled source (linear LDS dest)
#pragma unroll
    for (int c = 0; c < 2; ++c) {
      const int e = (c * 512 + tid) * 8;
      const int row = e >> 6;
      const int kvp = 32 * (row >> 5) + 8 * ((row >> 2) & 3) + 4 * ((row >> 4) & 1) + (row & 3);
      const int sb = ((e & 63) * 2) ^ ((row & 7) << 4);
      gload_lds16(Kg + (size_t)(kt * 128 + kvp) * 2304 + sb, lds_k + e);
    }
    // prefetch next V tile into regs
    if (kt < 15) {
#pragma unroll
      for (int j = 0; j < 2; ++j)
        vnxt[j] = *(const bf16x8*)(Vg + (size_t)((kt + 1) * 128 + vtok) * 2304 +
                                   (size_t)(vdg * 16 + j * 8) * 2);
    }
    // write current V tile transposed into LDS
#pragma unroll
    for (int j = 0; j < 2; ++j) {
      const unsigned short* pv = (const unsigned short*)&vcur[j];
#pragma unroll
      for (int u = 0; u < 8; ++u) {
        const int d = vdg * 16 + j * 8 + u;
        const int by = (d << 8) + (vtok << 1);
        *(unsigned short*)(lds_v + (by ^ ((d & 7) << 4))) = pv[u];
      }
    }
    __syncthreads();

    // QK^T swapped: s[f][i] = S[kv = 32*(f>>1) + 8g + 4*(f&1) + i][q]
    f32x4 s[8] = {};
#pragma unroll
    for (int kk = 0; kk < 2; ++kk) {
      const int sb = ((kk * 32 + g * 8) * 2) ^ ((q & 7) << 4);
      __builtin_amdgcn_s_setprio(1);
#pragma unroll
      for (int f = 0; f < 8; ++f) {
        const bf16x8 ak = *(const bf16x8*)((const char*)lds_k + (f * 16 + q) * 128 + sb);
        s[f] = MFMA16(ak, aq[kk], s[f]);
      }
      __builtin_amdgcn_s_setprio(0);
    }

    // lane-local softmax (exp2 domain), defer-max
    {
      f32x4 vm = s[0];
#pragma unroll
      for (int f = 1; f < 8; ++f) {
#pragma unroll
        for (int i = 0; i < 4; ++i) vm[i] = fmaxf(vm[i], s[f][i]);
      }
      float mx = fmaxf(fmaxf(vm[0], vm[1]), fmaxf(vm[2], vm[3]));
      mx = fmaxf(mx, __shfl_xor(mx, 16));
      mx = fmaxf(mx, __shfl_xor(mx, 32));
      if (!__all(mx <= m_run + 11.5f)) {
        const float mnew = fmaxf(m_run, mx);
        const float corr = exp2f(m_run - mnew);
        m_run = mnew;
        l_run *= corr;
#pragma unroll
        for (int n = 0; n < 4; ++n)
#pragma unroll
          for (int i = 0; i < 4; ++i) acc[n][i] *= corr;
      }
      f32x4 vs = {0.f, 0.f, 0.f, 0.f};
#pragma unroll
      for (int f = 0; f < 8; ++f)
#pragma unroll
        for (int i = 0; i < 4; ++i) {
          const float p = exp2f(s[f][i] - m_run);
          s[f][i] = p;
          vs[i] += p;
        }
      l_run += (vs[0] + vs[1]) + (vs[2] + vs[3]);   // per-lane partial
    }

    // pack P to bf16 pairs (in-lane B-frags thanks to K row permutation)
    unsigned pk[8][2];
#pragma unroll
    for (int f = 0; f < 8; ++f) {
      pk[f][0] = cvtpk(s[f][0], s[f][1]);
      pk[f][1] = cvtpk(s[f][2], s[f][3]);
    }

    // PV: acc[n] = O^T[d = n*16 + 4g + i][q]
#pragma unroll
    for (int st = 0; st < 4; ++st) {
      union { bf16x8 v; unsigned u[4]; } bp;
      bp.u[0] = pk[2 * st][0];
      bp.u[1] = pk[2 * st][1];
      bp.u[2] = pk[2 * st + 1][0];
      bp.u[3] = pk[2 * st + 1][1];
      const int cb = (st * 32 + g * 8) * 2;
      bf16x8 bv[4];
#pragma unroll
      for (int n = 0; n < 4; ++n) {
        const int d = n * 16 + q;
        bv[n] = *(const bf16x8*)(lds_v + d * 256 + (cb ^ ((d & 7) << 4)));
      }
      __builtin_amdgcn_s_setprio(1);
#pragma unroll
      for (int n = 0; n < 4; ++n)
        acc[n] = MFMA16(bv[n], bp.v, acc[n]);
      __builtin_amdgcn_s_setprio(0);
    }
    vcur[0] = vnxt[0];
    vcur[1] = vnxt[1];
  }

  // reduce l across the 4 g-lanes sharing q
  l_run += __shfl_xor(l_run, 16);
  l_run += __shfl_xor(l_run, 32);
  const float rl = 1.f / l_run;

  // transpose O^T -> O via LDS bounce ([128 q][64 d] bf16, 144B stride)
  __syncthreads();
  {
    char* lds_o = smem;
    const int row = w * 16 + q;
#pragma unroll
    for (int n = 0; n < 4; ++n)
#pragma unroll
      for (int i2 = 0; i2 < 2; ++i2) {
        const unsigned pr = cvtpk(acc[n][2 * i2] * rl, acc[n][2 * i2 + 1] * rl);
        *(unsigned*)(lds_o + row * 144 + n * 32 + g * 8 + i2 * 4) = pr;
      }
  }
  __syncthreads();
  {
    const char* lds_o = smem;
    const int row2 = tid >> 2;
    const int seg = tid & 3;
    const uint4 v0 = *(const uint4*)(lds_o + row2 * 144 + seg * 32);
    const uint4 v1 = *(const uint4*)(lds_o + row2 * 144 + seg * 32 + 16);
    bf16_t* dst = attn_out + ((size_t)(b * SEQ + qt * 128 + row2)) * H + h * HD + seg * 16;
    *(uint4*)dst = v0;
    *(uint4*)(dst + 8) = v1;
  }
}

// ---------------- launcher ---------------------------------------------------
extern "C" void kernel_launch(void* const* d_in, const int* in_sizes, int n_in,
                              void* d_out, int out_size, void* d_ws, size_t ws_size,
                              hipStream_t stream) {
  const float* x    = (const float*)d_in[0];
  const float* ln1w = (const float*)d_in[3];
  const float* q_w  = (const float*)d_in[4];
  const float* q_b  = (const float*)d_in[5];
  const float* k_w  = (const float*)d_in[6];
  const float* k_b  = (const float*)d_in[7];
  const float* v_w  = (const float*)d_in[8];
  const float* v_b  = (const float*)d_in[9];
  const float* o_w  = (const float*)d_in[10];
  const float* ln2w = (const float*)d_in[11];
  const float* g_w  = (const float*)d_in[12];
  const float* u_w  = (const float*)d_in[13];
  const float* dn_w = (const float*)d_in[14];
  float* out = (float*)d_out;

  char* ws = (char*)d_ws;
  bf16_t* wqkv = (bf16_t*)(ws + 0);         // 1152x896
  bf16_t* wo   = (bf16_t*)(ws + 2064384);   // 896x896
  bf16_t* wg   = (bf16_t*)(ws + 3670016);   // 4864x896
  bf16_t* wu   = (bf16_t*)(ws + 12386304);  // 4864x896
  bf16_t* wd   = (bf16_t*)(ws + 21102592);  // 896x4864
  float*  bqkv = (float*)(ws + 29818880);   // 1152
  bf16_t* hbuf = (bf16_t*)(ws + 29823488);  // 4096x896 (h1, then h2)
  bf16_t* qkv  = (bf16_t*)(ws + 37163520);  // 4096x1152
  bf16_t* attn = (bf16_t*)(ws + 46600704);  // 4096x896
  bf16_t* gu   = (bf16_t*)(ws + 53940736);  // 4096x4864

  cvt_all<<<14560, 256, 0, stream>>>(q_w, k_w, v_w, o_w, g_w, u_w, dn_w,
                                     wqkv, wo, wg, wu, wd);
  bias_cat_kernel<<<5, 256, 0, stream>>>(q_b, k_b, v_b, bqkv);

  // pre-norm attention
  rmsnorm_kernel<<<4096, 256, 0, stream>>>(x, ln1w, hbuf);
  gemm_bt<64, 0><<<576, 256, 0, stream>>>(hbuf, wqkv, qkv, nullptr, bqkv,
                                          nullptr, 4096, 1152, 896);
  attn_kernel<<<dim3(16, 14, 2), 512, 0, stream>>>(qkv, attn);
  gemm_bt<64, 1><<<448, 256, 0, stream>>>(attn, wo, nullptr, out, nullptr, x,
                                          4096, 896, 896);
  // pre-norm SwiGLU MLP
  rmsnorm_kernel<<<4096, 256, 0, stream>>>(out, ln2w, hbuf);
  gateup_kernel<<<2432, 256, 0, stream>>>(hbuf, wg, wu, gu);
  gemm_bt<64, 1><<<448, 256, 0, stream>>>(gu, wd, nullptr, out, nullptr, out,
                                          4096, 896, 4864);
}

// Round 4
// 286.687 us; speedup vs baseline: 1.4208x; 1.0751x over previous
//
#include <hip/hip_runtime.h>

#define H 896
#define NH 14
#define HD 64
#define DFF 4864
#define SEQ 2048
#define NTOK 4096
#define QKVN 1152
// ASCALE * log2(e), folded into q-weights/bias at conversion; softmax in exp2 domain
#define QSCALE 0.1803368801111244f

typedef unsigned short bf16_t;
typedef __attribute__((ext_vector_type(8))) short bf16x8;
typedef __attribute__((ext_vector_type(4))) float f32x4;

#define MFMA16(a, b, c) __builtin_amdgcn_mfma_f32_16x16x32_bf16(a, b, c, 0, 0, 0)

__device__ __forceinline__ unsigned short f2bf(float f) {
  unsigned u = __float_as_uint(f);
  u += 0x7fffu + ((u >> 16) & 1u);   // RNE
  return (unsigned short)(u >> 16);
}

__device__ __forceinline__ unsigned cvtpk(float lo, float hi) {
  unsigned r;
  asm("v_cvt_pk_bf16_f32 %0, %1, %2" : "=v"(r) : "v"(lo), "v"(hi));
  return r;
}

__device__ __forceinline__ void gload_lds16(const void* g, void* l) {
  __builtin_amdgcn_global_load_lds(
      (const __attribute__((address_space(1))) unsigned int*)g,
      (__attribute__((address_space(3))) unsigned int*)l, 16, 0, 0);
}

// ---------------- fused weight convert f32 -> bf16 ---------------------------
// q scaled by QSCALE; gate/up interleaved into wgu in 16-row groups:
// wgu row r: grp=r>>5, sub=r&31; sub<16 -> gate[grp*16+sub], else up[grp*16+sub-16]
__global__ void cvt_all(const float* __restrict__ q_w, const float* __restrict__ k_w,
                        const float* __restrict__ v_w, const float* __restrict__ o_w,
                        const float* __restrict__ g_w, const float* __restrict__ u_w,
                        const float* __restrict__ dn_w, bf16_t* __restrict__ wqkv,
                        bf16_t* __restrict__ wo, bf16_t* __restrict__ wgu,
                        bf16_t* __restrict__ wd) {
  const int bx = blockIdx.x;
  float sc = 1.f;
  if (bx < 1792) {
    const float* src; bf16_t* dst; int base;
    if (bx < 784)      { src = q_w; dst = wqkv;          base = 0;  sc = QSCALE; }
    else if (bx < 896) { src = k_w; dst = wqkv + 802816; base = 784; }
    else if (bx < 1008){ src = v_w; dst = wqkv + 917504; base = 896; }
    else               { src = o_w; dst = wo;            base = 1008; }
    const int i = ((bx - base) * 256 + threadIdx.x) * 4;
    const float4 v = *(const float4*)(src + i);
    uint2 o;
    o.x = (unsigned)f2bf(v.x * sc) | ((unsigned)f2bf(v.y * sc) << 16);
    o.y = (unsigned)f2bf(v.z * sc) | ((unsigned)f2bf(v.w * sc) << 16);
    *(uint2*)(dst + i) = o;
  } else if (bx < 10304) {
    // merged gate/up, dest-indexed
    const int i = ((bx - 1792) * 256 + threadIdx.x) * 4;
    const unsigned r = (unsigned)i / 896u;
    const int col = i - (int)r * 896;
    const int sub = r & 31;
    const unsigned srow = (r >> 5) * 16 + (sub & 15);
    const float* src = ((sub < 16) ? g_w : u_w) + (size_t)srow * 896 + col;
    const float4 v = *(const float4*)src;
    uint2 o;
    o.x = (unsigned)f2bf(v.x) | ((unsigned)f2bf(v.y) << 16);
    o.y = (unsigned)f2bf(v.z) | ((unsigned)f2bf(v.w) << 16);
    *(uint2*)(wgu + i) = o;
  } else {
    const int i = ((bx - 10304) * 256 + threadIdx.x) * 4;
    const float4 v = *(const float4*)(dn_w + i);
    uint2 o;
    o.x = (unsigned)f2bf(v.x) | ((unsigned)f2bf(v.y) << 16);
    o.y = (unsigned)f2bf(v.z) | ((unsigned)f2bf(v.w) << 16);
    *(uint2*)(wd + i) = o;
  }
}

__global__ void bias_cat_kernel(const float* __restrict__ qb, const float* __restrict__ kb,
                                const float* __restrict__ vb, float* __restrict__ out) {
  const int i = blockIdx.x * 256 + threadIdx.x;
  if (i < 1152)
    out[i] = (i < 896) ? qb[i] * QSCALE : ((i < 1024) ? kb[i - 896] : vb[i - 1024]);
}

// ---------------- RMSNorm: one block per row of 896, f32 in -> bf16 out ------
__global__ __launch_bounds__(256)
void rmsnorm_kernel(const float* __restrict__ x, const float* __restrict__ wt,
                    bf16_t* __restrict__ out) {
  const int row = blockIdx.x;
  const int t = threadIdx.x;
  float4 v = {0.f, 0.f, 0.f, 0.f};
  float ss = 0.f;
  const float4* xr = (const float4*)(x + (size_t)row * H);
  if (t < 224) {
    v = xr[t];
    ss = v.x * v.x + v.y * v.y + v.z * v.z + v.w * v.w;
  }
#pragma unroll
  for (int m = 32; m; m >>= 1) ss += __shfl_xor(ss, m);
  __shared__ float wsum[4];
  if ((t & 63) == 0) wsum[t >> 6] = ss;
  __syncthreads();
  const float rinv = rsqrtf((wsum[0] + wsum[1] + wsum[2] + wsum[3]) * (1.f / 896.f) + 1e-5f);
  if (t < 224) {
    const float4 wv = ((const float4*)wt)[t];
    uint2 o;
    o.x = (unsigned)f2bf(v.x * rinv * wv.x) | ((unsigned)f2bf(v.y * rinv * wv.y) << 16);
    o.y = (unsigned)f2bf(v.z * rinv * wv.z) | ((unsigned)f2bf(v.w * rinv * wv.w) << 16);
    ((uint2*)(out + (size_t)row * H))[t] = o;
  }
}

// ---------------- GEMM out[M][N] = A[M][K] @ B[N][K]^T (+bias | +res) --------
// BM x 128 tile, BK=64, 4 waves (2x2). T3-min pipelined double-buffer:
// stage(next) issued BEFORE compute(cur); ONE barrier per k-step (implicit
// vmcnt(0)+lgkmcnt(0) drain). Source-pre-swizzled staging (col ^= (row&7)*8
// elems), swizzled frag reads -> all-32-bank-even LDS access. XCD swizzle.
template <int BM, int EPI>
__global__ __launch_bounds__(256, BM == 64 ? 3 : 2)
void gemm_bt(const bf16_t* __restrict__ A, const bf16_t* __restrict__ Bw,
             bf16_t* __restrict__ outb, float* __restrict__ outf,
             const float* __restrict__ bias, const float* __restrict__ res,
             int M, int N, int K) {
  __shared__ bf16_t As[2][BM * 64];
  __shared__ bf16_t Bs[2][128 * 64];
  const int tid = threadIdx.x;
  const int lane = tid & 63;
  const int q = lane & 15;
  const int g = lane >> 4;
  const int w = tid >> 6;
  const int wr = w >> 1, wc = w & 1;
  const int local = blockIdx.x >> 3;
  const int xcd = blockIdx.x & 7;
  const int m0 = (xcd * 8 + (local & 7)) * BM;
  const int n0 = (local >> 3) * 128;
  const int MREP = BM / 32;
  const int ACH = BM / 32;
  const int NSTEP = K >> 6;

  f32x4 acc[BM / 32][4] = {};

#define STAGE_G(p, step)                                                        \
  {                                                                             \
    const int k0 = (step) << 6;                                                 \
    _Pragma("unroll") for (int c = 0; c < ACH; ++c) {                           \
      const int e = (c * 256 + tid) * 8;                                        \
      const int r = e >> 6;                                                     \
      const int csw = (e & 63) ^ ((r & 7) << 3);                                \
      gload_lds16(A + (size_t)(m0 + r) * K + (k0 + csw), As[p] + e);            \
    }                                                                           \
    _Pragma("unroll") for (int c = 0; c < 4; ++c) {                             \
      const int e = (c * 256 + tid) * 8;                                        \
      const int r = e >> 6;                                                     \
      const int csw = (e & 63) ^ ((r & 7) << 3);                                \
      gload_lds16(Bw + (size_t)(n0 + r) * K + (k0 + csw), Bs[p] + e);           \
    }                                                                           \
  }

  STAGE_G(0, 0);
  __syncthreads();
  int p = 0;
  for (int step = 0; step < NSTEP; ++step) {
    if (step + 1 < NSTEP) STAGE_G(p ^ 1, step + 1);
#pragma unroll
    for (int kk = 0; kk < 2; ++kk) {
      const int koff = (kk * 32 + g * 8) ^ ((q & 7) << 3);
      bf16x8 a[BM / 32], b[4];
#pragma unroll
      for (int m = 0; m < MREP; ++m)
        a[m] = *(const bf16x8*)(As[p] + (wr * (BM / 2) + m * 16 + q) * 64 + koff);
#pragma unroll
      for (int n = 0; n < 4; ++n)
        b[n] = *(const bf16x8*)(Bs[p] + (wc * 64 + n * 16 + q) * 64 + koff);
#pragma unroll
      for (int m = 0; m < MREP; ++m)
#pragma unroll
        for (int n = 0; n < 4; ++n)
          acc[m][n] = MFMA16(a[m], b[n], acc[m][n]);
    }
    __syncthreads();
    p ^= 1;
  }

#pragma unroll
  for (int m = 0; m < MREP; ++m) {
    const int row = m0 + wr * (BM / 2) + m * 16 + g * 4;
#pragma unroll
    for (int n = 0; n < 4; ++n) {
      const int col = n0 + wc * 64 + n * 16 + q;
      const float bv = (EPI == 0) ? bias[col] : 0.f;
#pragma unroll
      for (int i = 0; i < 4; ++i) {
        const size_t idx = (size_t)(row + i) * N + col;
        if (EPI == 0) outb[idx] = f2bf(acc[m][n][i] + bv);
        else          outf[idx] = acc[m][n][i] + res[idx];
      }
    }
  }
#undef STAGE_G
}

// ---------------- merged gate/up GEMM: plain 128x128 over interleaved wgu ----
// Frag pairs (n=0,1) and (n=2,3) are gate/up rows for the SAME dff rows ->
// in-lane silu(g)*u epilogue, zero shuffles/barriers. Same pipelined dbuf.
__global__ __launch_bounds__(256, 2)
void gateup_kernel(const bf16_t* __restrict__ A, const bf16_t* __restrict__ Wgu,
                   bf16_t* __restrict__ gu) {
  __shared__ bf16_t As[2][128 * 64];
  __shared__ bf16_t Bs[2][128 * 64];
  const int tid = threadIdx.x;
  const int lane = tid & 63;
  const int q = lane & 15;
  const int g = lane >> 4;
  const int w = tid >> 6;
  const int wr = w >> 1, wc = w & 1;
  const int local = blockIdx.x >> 3;   // 0..303
  const int xcd = blockIdx.x & 7;
  const int m0 = (xcd * 4 + (local & 3)) * 128;
  const int n0 = (local >> 2) * 128;

  f32x4 acc[4][4] = {};

#define STAGE_GU(p, step)                                                       \
  {                                                                             \
    const int k0 = (step) << 6;                                                 \
    _Pragma("unroll") for (int c = 0; c < 4; ++c) {                             \
      const int e = (c * 256 + tid) * 8;                                        \
      const int r = e >> 6;                                                     \
      const int csw = (e & 63) ^ ((r & 7) << 3);                                \
      gload_lds16(A + (size_t)(m0 + r) * 896 + (k0 + csw), As[p] + e);          \
      gload_lds16(Wgu + (size_t)(n0 + r) * 896 + (k0 + csw), Bs[p] + e);        \
    }                                                                           \
  }

  STAGE_GU(0, 0);
  __syncthreads();
  int p = 0;
  for (int step = 0; step < 14; ++step) {
    if (step + 1 < 14) STAGE_GU(p ^ 1, step + 1);
#pragma unroll
    for (int kk = 0; kk < 2; ++kk) {
      const int koff = (kk * 32 + g * 8) ^ ((q & 7) << 3);
      bf16x8 a[4], b[4];
#pragma unroll
      for (int m = 0; m < 4; ++m)
        a[m] = *(const bf16x8*)(As[p] + (wr * 64 + m * 16 + q) * 64 + koff);
#pragma unroll
      for (int n = 0; n < 4; ++n)
        b[n] = *(const bf16x8*)(Bs[p] + (wc * 64 + n * 16 + q) * 64 + koff);
#pragma unroll
      for (int m = 0; m < 4; ++m)
#pragma unroll
        for (int n = 0; n < 4; ++n)
          acc[m][n] = MFMA16(a[m], b[n], acc[m][n]);
    }
    __syncthreads();
    p ^= 1;
  }

#pragma unroll
  for (int m = 0; m < 4; ++m) {
    const int row = m0 + wr * 64 + m * 16 + g * 4;
#pragma unroll
    for (int pr = 0; pr < 2; ++pr) {
      const int dff = (n0 >> 1) + wc * 32 + pr * 16 + q;
#pragma unroll
      for (int i = 0; i < 4; ++i) {
        const float gv = acc[m][2 * pr][i];
        const float uv = acc[m][2 * pr + 1][i];
        const float r = (gv / (1.f + __expf(-gv))) * uv;
        gu[(size_t)(row + i) * DFF + dff] = f2bf(r);
      }
    }
  }
#undef STAGE_GU
}

// ---------------- flash attention v3: swapped QK^T, lane-local softmax -------
__global__ __launch_bounds__(512, 4)
void attn_kernel(const bf16_t* __restrict__ qkv, bf16_t* __restrict__ attn_out) {
  __shared__ __align__(16) char smem[32768];
  bf16_t* lds_k = (bf16_t*)smem;          // 16 KB: Q tile, then K tiles
  char* lds_v = smem + 16384;             // 16 KB: V^T
  const int tid = threadIdx.x;
  const int lane = tid & 63;
  const int q = lane & 15;
  const int g = lane >> 4;
  const int w = tid >> 6;
  const int qt = blockIdx.x;
  const int h = blockIdx.y;
  const int b = blockIdx.z;
  const int kvh = h / 7;
  const char* Qg = (const char*)(qkv + (size_t)(b * SEQ + qt * 128) * QKVN + h * HD);
  const char* Kg = (const char*)(qkv + (size_t)(b * SEQ) * QKVN + H + kvh * HD);
  const char* Vg = (const char*)(qkv + (size_t)(b * SEQ) * QKVN + 1024 + kvh * HD);

#pragma unroll
  for (int c = 0; c < 2; ++c) {
    const int e = (c * 512 + tid) * 8;
    const int tok = e >> 6;
    const int sb = ((e & 63) * 2) ^ ((tok & 7) << 4);
    gload_lds16(Qg + (size_t)tok * 2304 + sb, lds_k + e);
  }
  __syncthreads();
  bf16x8 aq[2];
  {
    const int qrow = w * 16 + q;
#pragma unroll
    for (int kk = 0; kk < 2; ++kk) {
      const int sb = ((kk * 32 + g * 8) * 2) ^ ((qrow & 7) << 4);
      aq[kk] = *(const bf16x8*)((const char*)lds_k + qrow * 128 + sb);
    }
  }

  const int vtok = (w & 1) * 64 + lane;
  const int vdg = w >> 1;

  bf16x8 vcur[2], vnxt[2];
#pragma unroll
  for (int j = 0; j < 2; ++j)
    vcur[j] = *(const bf16x8*)(Vg + (size_t)vtok * 2304 + (size_t)(vdg * 16 + j * 8) * 2);

  float m_run = -1.0e30f, l_run = 0.f;
  f32x4 acc[4] = {};

  for (int kt = 0; kt < 16; ++kt) {
    __syncthreads();
#pragma unroll
    for (int c = 0; c < 2; ++c) {
      const int e = (c * 512 + tid) * 8;
      const int row = e >> 6;
      const int kvp = 32 * (row >> 5) + 8 * ((row >> 2) & 3) + 4 * ((row >> 4) & 1) + (row & 3);
      const int sb = ((e & 63) * 2) ^ ((row & 7) << 4);
      gload_lds16(Kg + (size_t)(kt * 128 + kvp) * 2304 + sb, lds_k + e);
    }
    if (kt < 15) {
#pragma unroll
      for (int j = 0; j < 2; ++j)
        vnxt[j] = *(const bf16x8*)(Vg + (size_t)((kt + 1) * 128 + vtok) * 2304 +
                                   (size_t)(vdg * 16 + j * 8) * 2);
    }
#pragma unroll
    for (int j = 0; j < 2; ++j) {
      const unsigned short* pv = (const unsigned short*)&vcur[j];
#pragma unroll
      for (int u = 0; u < 8; ++u) {
        const int d = vdg * 16 + j * 8 + u;
        const int by = (d << 8) + (vtok << 1);
        *(unsigned short*)(lds_v + (by ^ ((d & 7) << 4))) = pv[u];
      }
    }
    __syncthreads();

    f32x4 s[8] = {};
#pragma unroll
    for (int kk = 0; kk < 2; ++kk) {
      const int sb = ((kk * 32 + g * 8) * 2) ^ ((q & 7) << 4);
      __builtin_amdgcn_s_setprio(1);
#pragma unroll
      for (int f = 0; f < 8; ++f) {
        const bf16x8 ak = *(const bf16x8*)((const char*)lds_k + (f * 16 + q) * 128 + sb);
        s[f] = MFMA16(ak, aq[kk], s[f]);
      }
      __builtin_amdgcn_s_setprio(0);
    }

    {
      f32x4 vm = s[0];
#pragma unroll
      for (int f = 1; f < 8; ++f) {
#pragma unroll
        for (int i = 0; i < 4; ++i) vm[i] = fmaxf(vm[i], s[f][i]);
      }
      float mx = fmaxf(fmaxf(vm[0], vm[1]), fmaxf(vm[2], vm[3]));
      mx = fmaxf(mx, __shfl_xor(mx, 16));
      mx = fmaxf(mx, __shfl_xor(mx, 32));
      if (!__all(mx <= m_run + 11.5f)) {
        const float mnew = fmaxf(m_run, mx);
        const float corr = exp2f(m_run - mnew);
        m_run = mnew;
        l_run *= corr;
#pragma unroll
        for (int n = 0; n < 4; ++n)
#pragma unroll
          for (int i = 0; i < 4; ++i) acc[n][i] *= corr;
      }
      f32x4 vs = {0.f, 0.f, 0.f, 0.f};
#pragma unroll
      for (int f = 0; f < 8; ++f)
#pragma unroll
        for (int i = 0; i < 4; ++i) {
          const float p = exp2f(s[f][i] - m_run);
          s[f][i] = p;
          vs[i] += p;
        }
      l_run += (vs[0] + vs[1]) + (vs[2] + vs[3]);
    }

    unsigned pk[8][2];
#pragma unroll
    for (int f = 0; f < 8; ++f) {
      pk[f][0] = cvtpk(s[f][0], s[f][1]);
      pk[f][1] = cvtpk(s[f][2], s[f][3]);
    }

#pragma unroll
    for (int st = 0; st < 4; ++st) {
      union { bf16x8 v; unsigned u[4]; } bp;
      bp.u[0] = pk[2 * st][0];
      bp.u[1] = pk[2 * st][1];
      bp.u[2] = pk[2 * st + 1][0];
      bp.u[3] = pk[2 * st + 1][1];
      const int cb = (st * 32 + g * 8) * 2;
      bf16x8 bv[4];
#pragma unroll
      for (int n = 0; n < 4; ++n) {
        const int d = n * 16 + q;
        bv[n] = *(const bf16x8*)(lds_v + d * 256 + (cb ^ ((d & 7) << 4)));
      }
      __builtin_amdgcn_s_setprio(1);
#pragma unroll
      for (int n = 0; n < 4; ++n)
        acc[n] = MFMA16(bv[n], bp.v, acc[n]);
      __builtin_amdgcn_s_setprio(0);
    }
    vcur[0] = vnxt[0];
    vcur[1] = vnxt[1];
  }

  l_run += __shfl_xor(l_run, 16);
  l_run += __shfl_xor(l_run, 32);
  const float rl = 1.f / l_run;

  __syncthreads();
  {
    char* lds_o = smem;
    const int row = w * 16 + q;
#pragma unroll
    for (int n = 0; n < 4; ++n)
#pragma unroll
      for (int i2 = 0; i2 < 2; ++i2) {
        const unsigned pr = cvtpk(acc[n][2 * i2] * rl, acc[n][2 * i2 + 1] * rl);
        *(unsigned*)(lds_o + row * 144 + n * 32 + g * 8 + i2 * 4) = pr;
      }
  }
  __syncthreads();
  {
    const char* lds_o = smem;
    const int row2 = tid >> 2;
    const int seg = tid & 3;
    const uint4 v0 = *(const uint4*)(lds_o + row2 * 144 + seg * 32);
    const uint4 v1 = *(const uint4*)(lds_o + row2 * 144 + seg * 32 + 16);
    bf16_t* dst = attn_out + ((size_t)(b * SEQ + qt * 128 + row2)) * H + h * HD + seg * 16;
    *(uint4*)dst = v0;
    *(uint4*)(dst + 8) = v1;
  }
}

// ---------------- launcher ---------------------------------------------------
extern "C" void kernel_launch(void* const* d_in, const int* in_sizes, int n_in,
                              void* d_out, int out_size, void* d_ws, size_t ws_size,
                              hipStream_t stream) {
  const float* x    = (const float*)d_in[0];
  const float* ln1w = (const float*)d_in[3];
  const float* q_w  = (const float*)d_in[4];
  const float* q_b  = (const float*)d_in[5];
  const float* k_w  = (const float*)d_in[6];
  const float* k_b  = (const float*)d_in[7];
  const float* v_w  = (const float*)d_in[8];
  const float* v_b  = (const float*)d_in[9];
  const float* o_w  = (const float*)d_in[10];
  const float* ln2w = (const float*)d_in[11];
  const float* g_w  = (const float*)d_in[12];
  const float* u_w  = (const float*)d_in[13];
  const float* dn_w = (const float*)d_in[14];
  float* out = (float*)d_out;

  char* ws = (char*)d_ws;
  bf16_t* wqkv = (bf16_t*)(ws + 0);         // 1152x896
  bf16_t* wo   = (bf16_t*)(ws + 2064384);   // 896x896
  bf16_t* wgu  = (bf16_t*)(ws + 3670016);   // 9728x896 (interleaved gate/up)
  bf16_t* wd   = (bf16_t*)(ws + 21102592);  // 896x4864
  float*  bqkv = (float*)(ws + 29818880);   // 1152
  bf16_t* hbuf = (bf16_t*)(ws + 29823488);  // 4096x896 (h1, then h2)
  bf16_t* qkv  = (bf16_t*)(ws + 37163520);  // 4096x1152
  bf16_t* attn = (bf16_t*)(ws + 46600704);  // 4096x896
  bf16_t* gu   = (bf16_t*)(ws + 53940736);  // 4096x4864

  cvt_all<<<14560, 256, 0, stream>>>(q_w, k_w, v_w, o_w, g_w, u_w, dn_w,
                                     wqkv, wo, wgu, wd);
  bias_cat_kernel<<<5, 256, 0, stream>>>(q_b, k_b, v_b, bqkv);

  // pre-norm attention
  rmsnorm_kernel<<<4096, 256, 0, stream>>>(x, ln1w, hbuf);
  gemm_bt<64, 0><<<576, 256, 0, stream>>>(hbuf, wqkv, qkv, nullptr, bqkv,
                                          nullptr, 4096, 1152, 896);
  attn_kernel<<<dim3(16, 14, 2), 512, 0, stream>>>(qkv, attn);
  gemm_bt<64, 1><<<448, 256, 0, stream>>>(attn, wo, nullptr, out, nullptr, x,
                                          4096, 896, 896);
  // pre-norm SwiGLU MLP
  rmsnorm_kernel<<<4096, 256, 0, stream>>>(out, ln2w, hbuf);
  gateup_kernel<<<2432, 256, 0, stream>>>(hbuf, wgu, gu);
  gemm_bt<64, 1><<<448, 256, 0, stream>>>(gu, wd, nullptr, out, nullptr, out,
                                          4096, 896, 4864);
}

// Round 5
// 260.588 us; speedup vs baseline: 1.5631x; 1.1002x over previous
//
#include <hip/hip_runtime.h>

#define H 896
#define NH 14
#define HD 64
#define DFF 4864
#define SEQ 2048
#define NTOK 4096
#define QKVN 1152
// ASCALE * log2(e), folded into q-weights/bias at conversion; softmax in exp2 domain
#define QSCALE 0.1803368801111244f

typedef unsigned short bf16_t;
typedef __attribute__((ext_vector_type(8))) short bf16x8;
typedef __attribute__((ext_vector_type(4))) float f32x4;

#define MFMA16(a, b, c) __builtin_amdgcn_mfma_f32_16x16x32_bf16(a, b, c, 0, 0, 0)

__device__ __forceinline__ unsigned short f2bf(float f) {
  unsigned u = __float_as_uint(f);
  u += 0x7fffu + ((u >> 16) & 1u);   // RNE
  return (unsigned short)(u >> 16);
}

__device__ __forceinline__ float bf2f(unsigned short h) {
  return __uint_as_float((unsigned)h << 16);
}

__device__ __forceinline__ unsigned cvtpk(float lo, float hi) {
  unsigned r;
  asm("v_cvt_pk_bf16_f32 %0, %1, %2" : "=v"(r) : "v"(lo), "v"(hi));
  return r;
}

__device__ __forceinline__ void gload_lds16(const void* g, void* l) {
  __builtin_amdgcn_global_load_lds(
      (const __attribute__((address_space(1))) unsigned int*)g,
      (__attribute__((address_space(3))) unsigned int*)l, 16, 0, 0);
}

// ---------------- fused weight convert f32 -> bf16 ---------------------------
__global__ void cvt_all(const float* __restrict__ q_w, const float* __restrict__ k_w,
                        const float* __restrict__ v_w, const float* __restrict__ o_w,
                        const float* __restrict__ g_w, const float* __restrict__ u_w,
                        const float* __restrict__ dn_w, bf16_t* __restrict__ wqkv,
                        bf16_t* __restrict__ wo, bf16_t* __restrict__ wgu,
                        bf16_t* __restrict__ wd) {
  const int bx = blockIdx.x;
  float sc = 1.f;
  if (bx < 1792) {
    const float* src; bf16_t* dst; int base;
    if (bx < 784)      { src = q_w; dst = wqkv;          base = 0;  sc = QSCALE; }
    else if (bx < 896) { src = k_w; dst = wqkv + 802816; base = 784; }
    else if (bx < 1008){ src = v_w; dst = wqkv + 917504; base = 896; }
    else               { src = o_w; dst = wo;            base = 1008; }
    const int i = ((bx - base) * 256 + threadIdx.x) * 4;
    const float4 v = *(const float4*)(src + i);
    uint2 o;
    o.x = (unsigned)f2bf(v.x * sc) | ((unsigned)f2bf(v.y * sc) << 16);
    o.y = (unsigned)f2bf(v.z * sc) | ((unsigned)f2bf(v.w * sc) << 16);
    *(uint2*)(dst + i) = o;
  } else if (bx < 10304) {
    // merged gate/up, dest-indexed: wgu row r: grp=r>>5, sub=r&31
    const int i = ((bx - 1792) * 256 + threadIdx.x) * 4;
    const unsigned r = (unsigned)i / 896u;
    const int col = i - (int)r * 896;
    const int sub = r & 31;
    const unsigned srow = (r >> 5) * 16 + (sub & 15);
    const float* src = ((sub < 16) ? g_w : u_w) + (size_t)srow * 896 + col;
    const float4 v = *(const float4*)src;
    uint2 o;
    o.x = (unsigned)f2bf(v.x) | ((unsigned)f2bf(v.y) << 16);
    o.y = (unsigned)f2bf(v.z) | ((unsigned)f2bf(v.w) << 16);
    *(uint2*)(wgu + i) = o;
  } else {
    const int i = ((bx - 10304) * 256 + threadIdx.x) * 4;
    const float4 v = *(const float4*)(dn_w + i);
    uint2 o;
    o.x = (unsigned)f2bf(v.x) | ((unsigned)f2bf(v.y) << 16);
    o.y = (unsigned)f2bf(v.z) | ((unsigned)f2bf(v.w) << 16);
    *(uint2*)(wd + i) = o;
  }
}

__global__ void bias_cat_kernel(const float* __restrict__ qb, const float* __restrict__ kb,
                                const float* __restrict__ vb, float* __restrict__ out) {
  const int i = blockIdx.x * 256 + threadIdx.x;
  if (i < 1152)
    out[i] = (i < 896) ? qb[i] * QSCALE : ((i < 1024) ? kb[i - 896] : vb[i - 1024]);
}

// ---------------- RMSNorm: one block per row of 896, f32 in -> bf16 out ------
__global__ __launch_bounds__(256)
void rmsnorm_kernel(const float* __restrict__ x, const float* __restrict__ wt,
                    bf16_t* __restrict__ out) {
  const int row = blockIdx.x;
  const int t = threadIdx.x;
  float4 v = {0.f, 0.f, 0.f, 0.f};
  float ss = 0.f;
  const float4* xr = (const float4*)(x + (size_t)row * H);
  if (t < 224) {
    v = xr[t];
    ss = v.x * v.x + v.y * v.y + v.z * v.z + v.w * v.w;
  }
#pragma unroll
  for (int m = 32; m; m >>= 1) ss += __shfl_xor(ss, m);
  __shared__ float wsum[4];
  if ((t & 63) == 0) wsum[t >> 6] = ss;
  __syncthreads();
  const float rinv = rsqrtf((wsum[0] + wsum[1] + wsum[2] + wsum[3]) * (1.f / 896.f) + 1e-5f);
  if (t < 224) {
    const float4 wv = ((const float4*)wt)[t];
    uint2 o;
    o.x = (unsigned)f2bf(v.x * rinv * wv.x) | ((unsigned)f2bf(v.y * rinv * wv.y) << 16);
    o.y = (unsigned)f2bf(v.z * rinv * wv.z) | ((unsigned)f2bf(v.w * rinv * wv.w) << 16);
    ((uint2*)(out + (size_t)row * H))[t] = o;
  }
}

// ---------------- GEMM out[M][N] = A[M][K'] @ B[N][K']^T ---------------------
// BM x 128 tile, BK=64, 4 waves (2x2). Counted-vmcnt pipelined double-buffer:
// per step: STAGE(t+1); s_waitcnt vmcnt(L) [tile t landed, t+1 in flight];
// s_barrier; ds_read+MFMA; s_barrier [WAR before stage t+2 overwrites].
// Loads get a full k-step of latency slack; queue never drains mid-loop.
// EPI 0: bf16 out + bias (qkv). EPI 1: f32 out = acc + res. EPI 2: split-K
// bf16 partials (grid decodes ks; kbase = ks*K).
template <int BM, int EPI>
__global__ __launch_bounds__(256, BM == 64 ? 3 : 2)
void gemm_bt(const bf16_t* __restrict__ A, const bf16_t* __restrict__ Bw,
             bf16_t* __restrict__ outb, float* __restrict__ outf,
             const float* __restrict__ bias, const float* __restrict__ res,
             int M, int N, int K, int lda, int ldb) {
  __shared__ bf16_t As[2][BM * 64];
  __shared__ bf16_t Bs[2][128 * 64];
  const int tid = threadIdx.x;
  const int lane = tid & 63;
  const int q = lane & 15;
  const int g = lane >> 4;
  const int w = tid >> 6;
  const int wr = w >> 1, wc = w & 1;
  const int local = blockIdx.x >> 3;
  const int xcd = blockIdx.x & 7;
  int m0, n0, kbase = 0;
  size_t pofs = 0;
  if (EPI == 2) {       // split-K decode: local = n*8 + m_l*2 + ks (BM=128)
    const int rem = local & 7;
    m0 = (xcd * 4 + (rem >> 1)) * BM;
    n0 = (local >> 3) * 128;
    kbase = (rem & 1) * K;
    pofs = (size_t)(rem & 1) * M * N;
  } else {
    m0 = (xcd * 8 + (local & 7)) * BM;
    n0 = (local >> 3) * 128;
  }
  const int MREP = BM / 32;
  const int ACH = BM / 32;
  const int NSTEP = K >> 6;

  f32x4 acc[BM / 32][4] = {};

#define STAGE_G(p, step)                                                        \
  {                                                                             \
    const int k0 = kbase + ((step) << 6);                                       \
    _Pragma("unroll") for (int c = 0; c < ACH; ++c) {                           \
      const int e = (c * 256 + tid) * 8;                                        \
      const int r = e >> 6;                                                     \
      const int csw = (e & 63) ^ ((r & 7) << 3);                                \
      gload_lds16(A + (size_t)(m0 + r) * lda + (k0 + csw), As[p] + e);          \
    }                                                                           \
    _Pragma("unroll") for (int c = 0; c < 4; ++c) {                             \
      const int e = (c * 256 + tid) * 8;                                        \
      const int r = e >> 6;                                                     \
      const int csw = (e & 63) ^ ((r & 7) << 3);                                \
      gload_lds16(Bw + (size_t)(n0 + r) * ldb + (k0 + csw), Bs[p] + e);         \
    }                                                                           \
  }

  STAGE_G(0, 0);
  int p = 0;
  for (int step = 0; step < NSTEP; ++step) {
    if (step + 1 < NSTEP) {
      STAGE_G(p ^ 1, step + 1);
      if constexpr (BM == 64) asm volatile("s_waitcnt vmcnt(6)" ::: "memory");
      else                    asm volatile("s_waitcnt vmcnt(8)" ::: "memory");
    } else {
      asm volatile("s_waitcnt vmcnt(0)" ::: "memory");
    }
    __builtin_amdgcn_s_barrier();
    __builtin_amdgcn_sched_barrier(0);
#pragma unroll
    for (int kk = 0; kk < 2; ++kk) {
      const int koff = (kk * 32 + g * 8) ^ ((q & 7) << 3);
      bf16x8 a[BM / 32], b[4];
#pragma unroll
      for (int m = 0; m < MREP; ++m)
        a[m] = *(const bf16x8*)(As[p] + (wr * (BM / 2) + m * 16 + q) * 64 + koff);
#pragma unroll
      for (int n = 0; n < 4; ++n)
        b[n] = *(const bf16x8*)(Bs[p] + (wc * 64 + n * 16 + q) * 64 + koff);
#pragma unroll
      for (int m = 0; m < MREP; ++m)
#pragma unroll
        for (int n = 0; n < 4; ++n)
          acc[m][n] = MFMA16(a[m], b[n], acc[m][n]);
    }
    __builtin_amdgcn_sched_barrier(0);
    __builtin_amdgcn_s_barrier();
    p ^= 1;
  }

#pragma unroll
  for (int m = 0; m < MREP; ++m) {
    const int row = m0 + wr * (BM / 2) + m * 16 + g * 4;
#pragma unroll
    for (int n = 0; n < 4; ++n) {
      const int col = n0 + wc * 64 + n * 16 + q;
      const float bv = (EPI == 0) ? bias[col] : 0.f;
#pragma unroll
      for (int i = 0; i < 4; ++i) {
        const size_t idx = (size_t)(row + i) * N + col;
        if (EPI == 0)      outb[idx] = f2bf(acc[m][n][i] + bv);
        else if (EPI == 1) outf[idx] = acc[m][n][i] + res[idx];
        else               outb[pofs + idx] = f2bf(acc[m][n][i]);
      }
    }
  }
#undef STAGE_G
}

// ---------------- split-K reduce: out += p0 + p1 (bf16 partials) -------------
__global__ __launch_bounds__(256)
void reduce_kernel(float* __restrict__ out, const bf16_t* __restrict__ part) {
  const int i = (blockIdx.x * 256 + threadIdx.x) * 4;
  const ushort4 a = *(const ushort4*)(part + i);
  const ushort4 b = *(const ushort4*)(part + 3670016 + i);
  float4 o = *(float4*)(out + i);
  o.x += bf2f(a.x) + bf2f(b.x);
  o.y += bf2f(a.y) + bf2f(b.y);
  o.z += bf2f(a.z) + bf2f(b.z);
  o.w += bf2f(a.w) + bf2f(b.w);
  *(float4*)(out + i) = o;
}

// ---------------- merged gate/up GEMM: 128x128 over interleaved wgu ----------
// Same counted-vmcnt pipeline. Frag pairs (n=0,1)/(n=2,3) are gate/up for the
// SAME dff rows -> in-lane silu(g)*u epilogue.
__global__ __launch_bounds__(256, 2)
void gateup_kernel(const bf16_t* __restrict__ A, const bf16_t* __restrict__ Wgu,
                   bf16_t* __restrict__ gu) {
  __shared__ bf16_t As[2][128 * 64];
  __shared__ bf16_t Bs[2][128 * 64];
  const int tid = threadIdx.x;
  const int lane = tid & 63;
  const int q = lane & 15;
  const int g = lane >> 4;
  const int w = tid >> 6;
  const int wr = w >> 1, wc = w & 1;
  const int local = blockIdx.x >> 3;   // 0..303
  const int xcd = blockIdx.x & 7;
  const int m0 = (xcd * 4 + (local & 3)) * 128;
  const int n0 = (local >> 2) * 128;

  f32x4 acc[4][4] = {};

#define STAGE_GU(p, step)                                                       \
  {                                                                             \
    const int k0 = (step) << 6;                                                 \
    _Pragma("unroll") for (int c = 0; c < 4; ++c) {                             \
      const int e = (c * 256 + tid) * 8;                                        \
      const int r = e >> 6;                                                     \
      const int csw = (e & 63) ^ ((r & 7) << 3);                                \
      gload_lds16(A + (size_t)(m0 + r) * 896 + (k0 + csw), As[p] + e);          \
      gload_lds16(Wgu + (size_t)(n0 + r) * 896 + (k0 + csw), Bs[p] + e);        \
    }                                                                           \
  }

  STAGE_GU(0, 0);
  int p = 0;
  for (int step = 0; step < 14; ++step) {
    if (step + 1 < 14) {
      STAGE_GU(p ^ 1, step + 1);
      asm volatile("s_waitcnt vmcnt(8)" ::: "memory");
    } else {
      asm volatile("s_waitcnt vmcnt(0)" ::: "memory");
    }
    __builtin_amdgcn_s_barrier();
    __builtin_amdgcn_sched_barrier(0);
#pragma unroll
    for (int kk = 0; kk < 2; ++kk) {
      const int koff = (kk * 32 + g * 8) ^ ((q & 7) << 3);
      bf16x8 a[4], b[4];
#pragma unroll
      for (int m = 0; m < 4; ++m)
        a[m] = *(const bf16x8*)(As[p] + (wr * 64 + m * 16 + q) * 64 + koff);
#pragma unroll
      for (int n = 0; n < 4; ++n)
        b[n] = *(const bf16x8*)(Bs[p] + (wc * 64 + n * 16 + q) * 64 + koff);
#pragma unroll
      for (int m = 0; m < 4; ++m)
#pragma unroll
        for (int n = 0; n < 4; ++n)
          acc[m][n] = MFMA16(a[m], b[n], acc[m][n]);
    }
    __builtin_amdgcn_sched_barrier(0);
    __builtin_amdgcn_s_barrier();
    p ^= 1;
  }

#pragma unroll
  for (int m = 0; m < 4; ++m) {
    const int row = m0 + wr * 64 + m * 16 + g * 4;
#pragma unroll
    for (int pr = 0; pr < 2; ++pr) {
      const int dff = (n0 >> 1) + wc * 32 + pr * 16 + q;
#pragma unroll
      for (int i = 0; i < 4; ++i) {
        const float gv = acc[m][2 * pr][i];
        const float uv = acc[m][2 * pr + 1][i];
        const float r = (gv / (1.f + __expf(-gv))) * uv;
        gu[(size_t)(row + i) * DFF + dff] = f2bf(r);
      }
    }
  }
#undef STAGE_GU
}

// ---------------- flash attention v3: swapped QK^T, lane-local softmax -------
__global__ __launch_bounds__(512, 4)
void attn_kernel(const bf16_t* __restrict__ qkv, bf16_t* __restrict__ attn_out) {
  __shared__ __align__(16) char smem[32768];
  bf16_t* lds_k = (bf16_t*)smem;          // 16 KB: Q tile, then K tiles
  char* lds_v = smem + 16384;             // 16 KB: V^T
  const int tid = threadIdx.x;
  const int lane = tid & 63;
  const int q = lane & 15;
  const int g = lane >> 4;
  const int w = tid >> 6;
  const int qt = blockIdx.x;
  const int h = blockIdx.y;
  const int b = blockIdx.z;
  const int kvh = h / 7;
  const char* Qg = (const char*)(qkv + (size_t)(b * SEQ + qt * 128) * QKVN + h * HD);
  const char* Kg = (const char*)(qkv + (size_t)(b * SEQ) * QKVN + H + kvh * HD);
  const char* Vg = (const char*)(qkv + (size_t)(b * SEQ) * QKVN + 1024 + kvh * HD);

#pragma unroll
  for (int c = 0; c < 2; ++c) {
    const int e = (c * 512 + tid) * 8;
    const int tok = e >> 6;
    const int sb = ((e & 63) * 2) ^ ((tok & 7) << 4);
    gload_lds16(Qg + (size_t)tok * 2304 + sb, lds_k + e);
  }
  __syncthreads();
  bf16x8 aq[2];
  {
    const int qrow = w * 16 + q;
#pragma unroll
    for (int kk = 0; kk < 2; ++kk) {
      const int sb = ((kk * 32 + g * 8) * 2) ^ ((qrow & 7) << 4);
      aq[kk] = *(const bf16x8*)((const char*)lds_k + qrow * 128 + sb);
    }
  }

  const int vtok = (w & 1) * 64 + lane;
  const int vdg = w >> 1;

  bf16x8 vcur[2], vnxt[2];
#pragma unroll
  for (int j = 0; j < 2; ++j)
    vcur[j] = *(const bf16x8*)(Vg + (size_t)vtok * 2304 + (size_t)(vdg * 16 + j * 8) * 2);

  float m_run = -1.0e30f, l_run = 0.f;
  f32x4 acc[4] = {};

  for (int kt = 0; kt < 16; ++kt) {
    __syncthreads();
#pragma unroll
    for (int c = 0; c < 2; ++c) {
      const int e = (c * 512 + tid) * 8;
      const int row = e >> 6;
      const int kvp = 32 * (row >> 5) + 8 * ((row >> 2) & 3) + 4 * ((row >> 4) & 1) + (row & 3);
      const int sb = ((e & 63) * 2) ^ ((row & 7) << 4);
      gload_lds16(Kg + (size_t)(kt * 128 + kvp) * 2304 + sb, lds_k + e);
    }
    if (kt < 15) {
#pragma unroll
      for (int j = 0; j < 2; ++j)
        vnxt[j] = *(const bf16x8*)(Vg + (size_t)((kt + 1) * 128 + vtok) * 2304 +
                                   (size_t)(vdg * 16 + j * 8) * 2);
    }
#pragma unroll
    for (int j = 0; j < 2; ++j) {
      const unsigned short* pv = (const unsigned short*)&vcur[j];
#pragma unroll
      for (int u = 0; u < 8; ++u) {
        const int d = vdg * 16 + j * 8 + u;
        const int by = (d << 8) + (vtok << 1);
        *(unsigned short*)(lds_v + (by ^ ((d & 7) << 4))) = pv[u];
      }
    }
    __syncthreads();

    f32x4 s[8] = {};
#pragma unroll
    for (int kk = 0; kk < 2; ++kk) {
      const int sb = ((kk * 32 + g * 8) * 2) ^ ((q & 7) << 4);
      __builtin_amdgcn_s_setprio(1);
#pragma unroll
      for (int f = 0; f < 8; ++f) {
        const bf16x8 ak = *(const bf16x8*)((const char*)lds_k + (f * 16 + q) * 128 + sb);
        s[f] = MFMA16(ak, aq[kk], s[f]);
      }
      __builtin_amdgcn_s_setprio(0);
    }

    {
      f32x4 vm = s[0];
#pragma unroll
      for (int f = 1; f < 8; ++f) {
#pragma unroll
        for (int i = 0; i < 4; ++i) vm[i] = fmaxf(vm[i], s[f][i]);
      }
      float mx = fmaxf(fmaxf(vm[0], vm[1]), fmaxf(vm[2], vm[3]));
      mx = fmaxf(mx, __shfl_xor(mx, 16));
      mx = fmaxf(mx, __shfl_xor(mx, 32));
      if (!__all(mx <= m_run + 11.5f)) {
        const float mnew = fmaxf(m_run, mx);
        const float corr = exp2f(m_run - mnew);
        m_run = mnew;
        l_run *= corr;
#pragma unroll
        for (int n = 0; n < 4; ++n)
#pragma unroll
          for (int i = 0; i < 4; ++i) acc[n][i] *= corr;
      }
      f32x4 vs = {0.f, 0.f, 0.f, 0.f};
#pragma unroll
      for (int f = 0; f < 8; ++f)
#pragma unroll
        for (int i = 0; i < 4; ++i) {
          const float p = exp2f(s[f][i] - m_run);
          s[f][i] = p;
          vs[i] += p;
        }
      l_run += (vs[0] + vs[1]) + (vs[2] + vs[3]);
    }

    unsigned pk[8][2];
#pragma unroll
    for (int f = 0; f < 8; ++f) {
      pk[f][0] = cvtpk(s[f][0], s[f][1]);
      pk[f][1] = cvtpk(s[f][2], s[f][3]);
    }

#pragma unroll
    for (int st = 0; st < 4; ++st) {
      union { bf16x8 v; unsigned u[4]; } bp;
      bp.u[0] = pk[2 * st][0];
      bp.u[1] = pk[2 * st][1];
      bp.u[2] = pk[2 * st + 1][0];
      bp.u[3] = pk[2 * st + 1][1];
      const int cb = (st * 32 + g * 8) * 2;
      bf16x8 bv[4];
#pragma unroll
      for (int n = 0; n < 4; ++n) {
        const int d = n * 16 + q;
        bv[n] = *(const bf16x8*)(lds_v + d * 256 + (cb ^ ((d & 7) << 4)));
      }
      __builtin_amdgcn_s_setprio(1);
#pragma unroll
      for (int n = 0; n < 4; ++n)
        acc[n] = MFMA16(bv[n], bp.v, acc[n]);
      __builtin_amdgcn_s_setprio(0);
    }
    vcur[0] = vnxt[0];
    vcur[1] = vnxt[1];
  }

  l_run += __shfl_xor(l_run, 16);
  l_run += __shfl_xor(l_run, 32);
  const float rl = 1.f / l_run;

  __syncthreads();
  {
    char* lds_o = smem;
    const int row = w * 16 + q;
#pragma unroll
    for (int n = 0; n < 4; ++n)
#pragma unroll
      for (int i2 = 0; i2 < 2; ++i2) {
        const unsigned pr = cvtpk(acc[n][2 * i2] * rl, acc[n][2 * i2 + 1] * rl);
        *(unsigned*)(lds_o + row * 144 + n * 32 + g * 8 + i2 * 4) = pr;
      }
  }
  __syncthreads();
  {
    const char* lds_o = smem;
    const int row2 = tid >> 2;
    const int seg = tid & 3;
    const uint4 v0 = *(const uint4*)(lds_o + row2 * 144 + seg * 32);
    const uint4 v1 = *(const uint4*)(lds_o + row2 * 144 + seg * 32 + 16);
    bf16_t* dst = attn_out + ((size_t)(b * SEQ + qt * 128 + row2)) * H + h * HD + seg * 16;
    *(uint4*)dst = v0;
    *(uint4*)(dst + 8) = v1;
  }
}

// ---------------- launcher ---------------------------------------------------
extern "C" void kernel_launch(void* const* d_in, const int* in_sizes, int n_in,
                              void* d_out, int out_size, void* d_ws, size_t ws_size,
                              hipStream_t stream) {
  const float* x    = (const float*)d_in[0];
  const float* ln1w = (const float*)d_in[3];
  const float* q_w  = (const float*)d_in[4];
  const float* q_b  = (const float*)d_in[5];
  const float* k_w  = (const float*)d_in[6];
  const float* k_b  = (const float*)d_in[7];
  const float* v_w  = (const float*)d_in[8];
  const float* v_b  = (const float*)d_in[9];
  const float* o_w  = (const float*)d_in[10];
  const float* ln2w = (const float*)d_in[11];
  const float* g_w  = (const float*)d_in[12];
  const float* u_w  = (const float*)d_in[13];
  const float* dn_w = (const float*)d_in[14];
  float* out = (float*)d_out;

  char* ws = (char*)d_ws;
  bf16_t* wqkv = (bf16_t*)(ws + 0);         // 1152x896
  bf16_t* wo   = (bf16_t*)(ws + 2064384);   // 896x896
  bf16_t* wgu  = (bf16_t*)(ws + 3670016);   // 9728x896 (interleaved gate/up)
  bf16_t* wd   = (bf16_t*)(ws + 21102592);  // 896x4864
  float*  bqkv = (float*)(ws + 29818880);   // 1152
  bf16_t* hbuf = (bf16_t*)(ws + 29823488);  // 4096x896 (h1, then h2)
  bf16_t* qkv  = (bf16_t*)(ws + 37163520);  // 4096x1152
  bf16_t* attn = (bf16_t*)(ws + 46600704);  // 4096x896
  bf16_t* gu   = (bf16_t*)(ws + 53940736);  // 4096x4864
  // split-K partials (bf16, 2x 4096x896) overlay dead bqkv/hbuf/qkv region
  bf16_t* part = (bf16_t*)(ws + 29818880);  // [29818880, 44498944)

  cvt_all<<<14560, 256, 0, stream>>>(q_w, k_w, v_w, o_w, g_w, u_w, dn_w,
                                     wqkv, wo, wgu, wd);
  bias_cat_kernel<<<5, 256, 0, stream>>>(q_b, k_b, v_b, bqkv);

  // pre-norm attention
  rmsnorm_kernel<<<4096, 256, 0, stream>>>(x, ln1w, hbuf);
  gemm_bt<64, 0><<<576, 256, 0, stream>>>(hbuf, wqkv, qkv, nullptr, bqkv,
                                          nullptr, 4096, 1152, 896, 896, 896);
  attn_kernel<<<dim3(16, 14, 2), 512, 0, stream>>>(qkv, attn);
  gemm_bt<64, 1><<<448, 256, 0, stream>>>(attn, wo, nullptr, out, nullptr, x,
                                          4096, 896, 896, 896, 896);
  // pre-norm SwiGLU MLP
  rmsnorm_kernel<<<4096, 256, 0, stream>>>(out, ln2w, hbuf);
  gateup_kernel<<<2432, 256, 0, stream>>>(hbuf, wgu, gu);
  // down-proj: split-K=2 bf16 partials + fused reduce(+residual)
  gemm_bt<128, 2><<<448, 256, 0, stream>>>(gu, wd, part, nullptr, nullptr, nullptr,
                                           4096, 896, 2432, 4864, 4864);
  reduce_kernel<<<3584, 256, 0, stream>>>(out, part);
}